// Round 6
// baseline (10362.302 us; speedup 1.0000x reference)
//
#include <hip/hip_runtime.h>
#include <hip/hip_bf16.h>
#include <math.h>

// Problem constants: T=512, B=64, D=512, H=1024, O=512
constexpr int T = 512;
constexpr int B = 64;
constexpr int D = 512;
constexpr int H = 1024;
constexpr int O = 512;
constexpr int NBLK = 128;          // persistent blocks, 1 per CU (LDS-bound)
constexpr int COLS = 32;           // gate-cols per block (8 hidden j's x 4 gates)
constexpr int KCH  = (D + H) / 8;  // 192 k-chunks of 8 elems
constexpr int AP   = 264;          // A_lds row stride (bf16 elems), 528B rows

typedef __attribute__((ext_vector_type(8))) __bf16 bf16x8;
typedef __attribute__((ext_vector_type(4))) float  floatx4;

// Tree barrier: 8 group counters (16 arrivals) -> root (8) -> flag. All relaxed;
// h visibility is physical (write-through stores, cache-bypass reads).
struct GBar {
    unsigned grp[8][32];
    unsigned root; unsigned p0[31];
    unsigned flag; unsigned p1[31];
};

// ---------------------------------------------------------------------------
// W' bf16, strip-major: Wc[strip(128)][kchunk(192)][nl(32)][8]; col reorder
// n = j*4+g. k<512 from Wx[g*H+j][k], else Wh[g*H+j][k-512].
// ---------------------------------------------------------------------------
__global__ __launch_bounds__(256) void convert_w(
    const float* __restrict__ Wx, const float* __restrict__ Wh,
    __bf16* __restrict__ Wc)
{
    const int id = blockIdx.x * 256 + threadIdx.x;   // 128*192*32 = 786432
    if (id >= NBLK * KCH * COLS) return;
    const int nl     = id & 31;
    const int kchunk = (id >> 5) % KCH;
    const int strip  = id / (KCH * COLS);
    const int n = strip * COLS + nl;
    const int j = n >> 2, g = n & 3;
    const int k0 = kchunk * 8;
    const float* src = (k0 < D) ? &Wx[(size_t)(g * H + j) * D + k0]
                                : &Wh[(size_t)(g * H + j) * H + (k0 - D)];
    const float4 a = *(const float4*)src;
    const float4 b = *(const float4*)(src + 4);
    __bf16 t8[8] = {(__bf16)a.x,(__bf16)a.y,(__bf16)a.z,(__bf16)a.w,
                    (__bf16)b.x,(__bf16)b.y,(__bf16)b.z,(__bf16)b.w};
    *(uint4*)&Wc[(size_t)id * 8] = *(uint4*)t8;
}

__global__ __launch_bounds__(256) void make_bias(
    const float* __restrict__ bx, const float* __restrict__ bh,
    float* __restrict__ bias)
{
    const int n = blockIdx.x * 256 + threadIdx.x;
    if (n < 4 * H) {
        const int j = n >> 2, g = n & 3;
        bias[n] = bx[g * H + j] + bh[g * H + j];
    }
}

// ---------------------------------------------------------------------------
// Persistent LSTM, round 6: COALESCED A-path. Round-5 counters showed the
// floor was per-lane 2KB-strided h/x reads (64 transactions per wave-load at
// L3). Now x and h are staged into an LDS A-buffer in 256-col chunks with
// consecutive-lane-consecutive-address loads (1 transaction per wave-load),
// and MFMA A-frags come from ds_read_b128. W in LDS, c in VGPRs, relaxed
// tree barrier, x-part overlap unchanged.
// ---------------------------------------------------------------------------
__global__ __launch_bounds__(256, 1) void lstm_persistent(
    const float* __restrict__ x,     // [T,B,D] fp32
    const __bf16* __restrict__ Wc,   // strip-major bf16 (read once at start)
    const float* __restrict__ bias,  // [4096] reordered
    __bf16* __restrict__ hb0,        // [B,H] bf16 ping
    __bf16* __restrict__ hb1,        // [B,H] bf16 pong
    float* __restrict__ hfin,        // [B,H] fp32 final h (aliases Wc head)
    GBar* bar)
{
    __shared__ __attribute__((aligned(16))) __bf16 wlds[KCH * COLS * 8]; // 96 KB
    __shared__ __attribute__((aligned(16))) __bf16 A_lds[64 * AP];       // 33 KB
    __shared__ __attribute__((aligned(16))) float  G[64][COLS + 4];      // 9.2 KB

    const int tid  = threadIdx.x;
    const int wid  = tid >> 6;     // wave id == m-tile (16 batch rows)
    const int lane = tid & 63;
    const int cm   = lane & 15;
    const int q    = lane >> 4;
    const int n0   = blockIdx.x * COLS;

    // ---- one-time: W strip -> LDS (6144 x 16B contiguous) ----
    {
        const uint4* wsrc = (const uint4*)(Wc + (size_t)blockIdx.x * KCH * COLS * 8);
        uint4* wdst = (uint4*)wlds;
        for (int i = tid; i < KCH * COLS; i += 256) wdst[i] = wsrc[i];
    }
    // epilogue mapping: thread owns (b=eb, j=jbase,jbase+1); c in registers
    const int eb = tid >> 2;
    const int p  = tid & 3;
    const int jbase = (n0 >> 2) + p * 2;
    const float4 bias0 = *(const float4*)&bias[n0 + p * 8];
    const float4 bias1 = *(const float4*)&bias[n0 + p * 8 + 4];
    float c0 = 0.f, c1 = 0.f;
    __syncthreads();

    const __bf16* wl = wlds + q * 256 + cm * 8;      // + sg*1024 (+128 strip1)
    floatx4 acc[2][2];  // [strip][k-parity]

    // MFMA over one staged 256-col chunk; kcg = global k-chunk index (0..5)
    auto mfma_chunk = [&](int kcg) {
        const __bf16* wb = wl + kcg * 8 * 1024;
        const __bf16* ab = &A_lds[(wid * 16 + cm) * AP + q * 8];
        #pragma unroll
        for (int s = 0; s < 8; ++s) {
            const bf16x8 af = *(const bf16x8*)(ab + s * 32);
            const bf16x8 b0 = *(const bf16x8*)(wb + s * 1024);
            const bf16x8 b1 = *(const bf16x8*)(wb + s * 1024 + 128);
            acc[0][s & 1] = __builtin_amdgcn_mfma_f32_16x16x32_bf16(af, b0, acc[0][s & 1], 0, 0, 0);
            acc[1][s & 1] = __builtin_amdgcn_mfma_f32_16x16x32_bf16(af, b1, acc[1][s & 1], 0, 0, 0);
        }
    };

    // stage 256 cols of x_t (fp32->bf16), coalesced: one row per wave-iter
    auto stage_x = [&](const float* xt, int kc) {
        #pragma unroll
        for (int r = 0; r < 16; ++r) {
            const int row = r * 4 + wid;
            const float4 v = *(const float4*)(xt + (size_t)row * D + kc * 256 + lane * 4);
            __bf16 t4[4] = {(__bf16)v.x, (__bf16)v.y, (__bf16)v.z, (__bf16)v.w};
            *(unsigned long long*)&A_lds[row * AP + lane * 4] = *(unsigned long long*)t4;
        }
    };

    // stage 256 cols of h (bf16, agent-scope coherent loads), coalesced
    auto stage_h = [&](const __bf16* hsrc, int kc) {
        #pragma unroll
        for (int r = 0; r < 16; ++r) {
            const int row = r * 4 + wid;
            const unsigned long long v = __hip_atomic_load(
                (const unsigned long long*)(hsrc + (size_t)row * H + kc * 256 + lane * 4),
                __ATOMIC_RELAXED, __HIP_MEMORY_SCOPE_AGENT);
            *(unsigned long long*)&A_lds[row * AP + lane * 4] = v;
        }
    };

    // x-part of step tt: zero acc, accumulate K=0..511 (h-independent)
    auto do_xpart = [&](int tt) {
        acc[0][0] = (floatx4){0,0,0,0}; acc[0][1] = (floatx4){0,0,0,0};
        acc[1][0] = (floatx4){0,0,0,0}; acc[1][1] = (floatx4){0,0,0,0};
        const float* xt = x + (size_t)tt * (B * D);
        #pragma unroll
        for (int kc = 0; kc < 2; ++kc) {
            stage_x(xt, kc);
            __syncthreads();
            mfma_chunk(kc);
            __syncthreads();
        }
    };

    do_xpart(0);

    for (int t = 0; t < T; ++t) {
        const __bf16* hcur = (t & 1) ? hb1 : hb0;
        __bf16*       hnxt = (t & 1) ? hb0 : hb1;

        // ---- wait for step t-1's h ----
        if (t > 0) {
            if (tid == 0) {
                while (__hip_atomic_load(&bar->flag, __ATOMIC_RELAXED,
                                         __HIP_MEMORY_SCOPE_AGENT) < (unsigned)t)
                    __builtin_amdgcn_s_sleep(1);
            }
            __syncthreads();
        }

        // ---- h-part: K = 512..1535, 4 staged chunks ----
        #pragma unroll
        for (int kc = 0; kc < 4; ++kc) {
            stage_h(hcur, kc);
            __syncthreads();
            mfma_chunk(2 + kc);
            __syncthreads();
        }
        const floatx4 av0 = acc[0][0] + acc[0][1];
        const floatx4 av1 = acc[1][0] + acc[1][1];

        // ---- transpose C via LDS ----
        #pragma unroll
        for (int r = 0; r < 4; ++r) {
            G[wid * 16 + q * 4 + r][cm]      = av0[r];
            G[wid * 16 + q * 4 + r][16 + cm] = av1[r];
        }
        __syncthreads();

        // ---- fused cell update: 2 (b,j) elems per thread ----
        const float4 g0 = *(const float4*)&G[eb][p * 8];
        const float4 g1 = *(const float4*)&G[eb][p * 8 + 4];
        const float i0 = 1.f / (1.f + expf(-(g0.x + bias0.x)));
        const float f0 = 1.f / (1.f + expf(-(g0.y + bias0.y)));
        const float o0 = 1.f / (1.f + expf(-(g0.z + bias0.z)));
        const float t0 = tanhf(g0.w + bias0.w);
        const float i1 = 1.f / (1.f + expf(-(g1.x + bias1.x)));
        const float f1 = 1.f / (1.f + expf(-(g1.y + bias1.y)));
        const float o1 = 1.f / (1.f + expf(-(g1.z + bias1.z)));
        const float t1 = tanhf(g1.w + bias1.w);
        c0 = f0 * c0 + i0 * t0;
        c1 = f1 * c1 + i1 * t1;
        const float hv0 = o0 * tanhf(c0);
        const float hv1 = o1 * tanhf(c1);
        const int hi = eb * H + jbase;
        union { __bf16 h2[2]; unsigned u; } hp;
        hp.h2[0] = (__bf16)hv0; hp.h2[1] = (__bf16)hv1;
        __hip_atomic_store((unsigned*)&hnxt[hi], hp.u, __ATOMIC_RELAXED,
                           __HIP_MEMORY_SCOPE_AGENT);   // write-through publish
        if (t == T - 1) { hfin[hi] = hv0; hfin[hi + 1] = hv1; }

        __syncthreads();  // G reads done + h stores vmcnt-drained before arrive

        // ---- arrive (relaxed tree), then overlap t+1's x-part ----
        if (tid == 0) {
            const int g = blockIdx.x >> 4;
            const unsigned old = __hip_atomic_fetch_add(&bar->grp[g][0], 1u,
                                    __ATOMIC_RELAXED, __HIP_MEMORY_SCOPE_AGENT);
            if (old == 16u * (unsigned)(t + 1) - 1u) {
                const unsigned r = __hip_atomic_fetch_add(&bar->root, 1u,
                                    __ATOMIC_RELAXED, __HIP_MEMORY_SCOPE_AGENT);
                if (r == 8u * (unsigned)(t + 1) - 1u) {
                    __hip_atomic_store(&bar->flag, (unsigned)(t + 1),
                                       __ATOMIC_RELAXED, __HIP_MEMORY_SCOPE_AGENT);
                }
            }
        }
        if (t + 1 < T) do_xpart(t + 1);
    }
}

// out[b,o] = h[b,:] . Why[o,:] + bhy[o]
__global__ __launch_bounds__(256) void out_gemm(
    const float* __restrict__ h, const float* __restrict__ Why,
    const float* __restrict__ bhy, float* __restrict__ out)
{
    const int idx = blockIdx.x * 256 + threadIdx.x;
    if (idx >= B * O) return;
    const int b = idx / O;
    const int o = idx % O;
    const float4* hv = (const float4*)&h[(size_t)b * H];
    const float4* wv = (const float4*)&Why[(size_t)o * H];
    float s = 0.f;
    #pragma unroll 4
    for (int k = 0; k < H / 4; ++k) {
        const float4 a = hv[k];
        const float4 w = wv[k];
        s += a.x * w.x + a.y * w.y + a.z * w.z + a.w * w.w;
    }
    out[idx] = s + bhy[o];
}

extern "C" void kernel_launch(void* const* d_in, const int* in_sizes, int n_in,
                              void* d_out, int out_size, void* d_ws, size_t ws_size,
                              hipStream_t stream) {
    const float* x   = (const float*)d_in[0];
    const float* Wx  = (const float*)d_in[1];
    const float* bx  = (const float*)d_in[2];
    const float* Wh  = (const float*)d_in[3];
    const float* bh  = (const float*)d_in[4];
    const float* Why = (const float*)d_in[5];
    const float* bhy = (const float*)d_in[6];
    float* out = (float*)d_out;

    // ws layout (12,863,488 B total):
    // Wc 12,582,912 | bias 16,384 | hb0 131,072 | bar 2,048 | hb1 131,072
    // hfin (256 KB fp32) aliases Wc[0:262144) — Wc only read during the
    // one-time LDS stage, 511 barriers before any t=T-1 write. Safe.
    char* ws = (char*)d_ws;
    __bf16* Wc   = (__bf16*)ws;
    float*  bias = (float*)(ws + 12582912);
    __bf16* hb0  = (__bf16*)(ws + 12599296);
    GBar*   bar  = (GBar*)  (ws + 12730368);
    __bf16* hb1  = (__bf16*)(ws + 12732416);
    float*  hfin = (float*)ws;

    hipMemsetAsync(ws + 12599296, 0, 131072 + 2048, stream);  // hb0 + bar
    convert_w<<<3072, 256, 0, stream>>>(Wx, Wh, Wc);
    make_bias<<<16, 256, 0, stream>>>(bx, bh, bias);

    lstm_persistent<<<NBLK, 256, 0, stream>>>(x, Wc, bias, hb0, hb1, hfin, bar);

    out_gemm<<<(B * O + 255) / 256, 256, 0, stream>>>(hfin, Why, bhy, out);
}

// Round 7
// 7269.805 us; speedup vs baseline: 1.4254x; 1.4254x over previous
//
#include <hip/hip_runtime.h>
#include <hip/hip_bf16.h>
#include <math.h>

// Problem constants: T=512, B=64, D=512, H=1024, O=512
constexpr int T = 512;
constexpr int B = 64;
constexpr int D = 512;
constexpr int H = 1024;
constexpr int O = 512;
constexpr int NBLK = 128;          // persistent blocks, 1 per CU (96KB LDS)
constexpr int COLS = 32;           // gate-cols per block (8 hidden j's x 4 gates)
constexpr int KCH  = (D + H) / 8;  // 192 k-chunks of 8 elems

typedef __attribute__((ext_vector_type(8))) __bf16 bf16x8;
typedef __attribute__((ext_vector_type(4))) float  floatx4;
typedef unsigned long long u64;

// Tree barrier: 8 group counters (16 arrivals) -> root (8) -> flag. All relaxed;
// h visibility is physical (write-through stores, cache-bypass reads).
struct GBar {
    unsigned grp[8][32];
    unsigned root; unsigned p0[31];
    unsigned flag; unsigned p1[31];
};

// ---------------------------------------------------------------------------
// W' bf16, strip-major: Wc[strip(128)][kchunk(192)][nl(32)][8]; col reorder
// n = j*4+g. k<512 from Wx[g*H+j][k], else Wh[g*H+j][k-512].
// ---------------------------------------------------------------------------
__global__ __launch_bounds__(256) void convert_w(
    const float* __restrict__ Wx, const float* __restrict__ Wh,
    __bf16* __restrict__ Wc)
{
    const int id = blockIdx.x * 256 + threadIdx.x;   // 128*192*32 = 786432
    if (id >= NBLK * KCH * COLS) return;
    const int nl     = id & 31;
    const int kchunk = (id >> 5) % KCH;
    const int strip  = id / (KCH * COLS);
    const int n = strip * COLS + nl;
    const int j = n >> 2, g = n & 3;
    const int k0 = kchunk * 8;
    const float* src = (k0 < D) ? &Wx[(size_t)(g * H + j) * D + k0]
                                : &Wh[(size_t)(g * H + j) * H + (k0 - D)];
    const float4 a = *(const float4*)src;
    const float4 b = *(const float4*)(src + 4);
    __bf16 t8[8] = {(__bf16)a.x,(__bf16)a.y,(__bf16)a.z,(__bf16)a.w,
                    (__bf16)b.x,(__bf16)b.y,(__bf16)b.z,(__bf16)b.w};
    *(uint4*)&Wc[(size_t)id * 8] = *(uint4*)t8;
}

__global__ __launch_bounds__(256) void make_bias(
    const float* __restrict__ bx, const float* __restrict__ bh,
    float* __restrict__ bias)
{
    const int n = blockIdx.x * 256 + threadIdx.x;
    if (n < 4 * H) {
        const int j = n >> 2, g = n & 3;
        bias[n] = bx[g * H + j] + bh[g * H + j];
    }
}

// ---------------------------------------------------------------------------
// Persistent LSTM, round 7: round-5 structure (best so far) + DEEP PREFETCH.
// Theory: round-5's floor was latency serialization of the 64 agent-scope
// atomic h-loads (and x loads) interleaved with dependent MFMAs. Here both
// h-part and x-part run an explicit 8-chunk-deep prefetch pipeline: group
// g+1's 16 loads are issued before group g's MFMAs consume their registers,
// keeping ~16 loads in flight (vmcnt pipelining). No extra syncs, no LDS
// staging (round-6 regression reverted).
// ---------------------------------------------------------------------------
__global__ __launch_bounds__(256, 1) void lstm_persistent(
    const float* __restrict__ x,     // [T,B,D] fp32
    const __bf16* __restrict__ Wc,   // strip-major bf16 (read once at start)
    const float* __restrict__ bias,  // [4096] reordered
    __bf16* __restrict__ hb0,        // [B,H] bf16 ping
    __bf16* __restrict__ hb1,        // [B,H] bf16 pong
    float* __restrict__ hfin,        // [B,H] fp32 final h (aliases Wc head)
    GBar* bar)
{
    __shared__ __attribute__((aligned(16))) __bf16 wlds[KCH * COLS * 8]; // 96 KB
    __shared__ __attribute__((aligned(16))) float  G[64][COLS + 4];      // 9.2 KB

    const int tid  = threadIdx.x;
    const int wid  = tid >> 6;     // wave id == m-tile (16 batch rows)
    const int lane = tid & 63;
    const int cm   = lane & 15;
    const int q    = lane >> 4;
    const int n0   = blockIdx.x * COLS;

    // ---- one-time: W strip -> LDS (6144 x 16B contiguous) ----
    {
        const uint4* wsrc = (const uint4*)(Wc + (size_t)blockIdx.x * KCH * COLS * 8);
        uint4* wdst = (uint4*)wlds;
        for (int i = tid; i < KCH * COLS; i += 256) wdst[i] = wsrc[i];
    }
    // epilogue mapping: thread owns (b=eb, j=jbase,jbase+1); c in registers
    const int eb = tid >> 2;
    const int p  = tid & 3;
    const int jbase = (n0 >> 2) + p * 2;
    const float4 bias0 = *(const float4*)&bias[n0 + p * 8];
    const float4 bias1 = *(const float4*)&bias[n0 + p * 8 + 4];
    float c0 = 0.f, c1 = 0.f;
    __syncthreads();

    const float* xrow = x + (size_t)(wid * 16 + cm) * D + q * 8;
    const int    hoff = (wid * 16 + cm) * H + q * 8;
    const __bf16* wl  = wlds + (q * 32 + cm) * 8;  // + s*1024 (+128 for strip1)

    floatx4 acc[2][2];  // [strip][k-parity]

    // x-part of step tt: K=0..511, 8-chunk-deep prefetch pipeline
    auto do_xpart = [&](int tt) {
        acc[0][0] = (floatx4){0,0,0,0}; acc[0][1] = (floatx4){0,0,0,0};
        acc[1][0] = (floatx4){0,0,0,0}; acc[1][1] = (floatx4){0,0,0,0};
        const float* xr = xrow + (size_t)tt * (B * D);
        float4 cur[8][2];
        #pragma unroll
        for (int s = 0; s < 8; ++s) {
            cur[s][0] = *(const float4*)(xr + s * 32);
            cur[s][1] = *(const float4*)(xr + s * 32 + 4);
        }
        #pragma unroll
        for (int g = 0; g < 2; ++g) {
            float4 nxt[8][2];
            if (g == 0) {
                #pragma unroll
                for (int s = 0; s < 8; ++s) {
                    nxt[s][0] = *(const float4*)(xr + (8 + s) * 32);
                    nxt[s][1] = *(const float4*)(xr + (8 + s) * 32 + 4);
                }
            }
            #pragma unroll
            for (int s = 0; s < 8; ++s) {
                const int sg = g * 8 + s;
                const float4 a0 = cur[s][0], a1 = cur[s][1];
                const bf16x8 af = {(__bf16)a0.x,(__bf16)a0.y,(__bf16)a0.z,(__bf16)a0.w,
                                   (__bf16)a1.x,(__bf16)a1.y,(__bf16)a1.z,(__bf16)a1.w};
                const bf16x8 b0 = *(const bf16x8*)(wl + sg * 1024);
                const bf16x8 b1 = *(const bf16x8*)(wl + sg * 1024 + 128);
                acc[0][sg & 1] = __builtin_amdgcn_mfma_f32_16x16x32_bf16(af, b0, acc[0][sg & 1], 0, 0, 0);
                acc[1][sg & 1] = __builtin_amdgcn_mfma_f32_16x16x32_bf16(af, b1, acc[1][sg & 1], 0, 0, 0);
            }
            if (g == 0) {
                #pragma unroll
                for (int s = 0; s < 8; ++s) { cur[s][0] = nxt[s][0]; cur[s][1] = nxt[s][1]; }
            }
        }
    };

    do_xpart(0);

    for (int t = 0; t < T; ++t) {
        const __bf16* hcur = (t & 1) ? hb1 : hb0;
        __bf16*       hnxt = (t & 1) ? hb0 : hb1;

        // ---- wait for step t-1's h ----
        if (t > 0) {
            if (tid == 0) {
                while (__hip_atomic_load(&bar->flag, __ATOMIC_RELAXED,
                                         __HIP_MEMORY_SCOPE_AGENT) < (unsigned)t)
                    __builtin_amdgcn_s_sleep(1);
            }
            __syncthreads();
        }

        // ---- h-part: K=512..1535, 32 chunks, 8-deep prefetch pipeline ----
        const u64* hr = (const u64*)(hcur + hoff);
        {
            u64 hv[8][2];
            #pragma unroll
            for (int s = 0; s < 8; ++s) {
                hv[s][0] = __hip_atomic_load(hr + s * 8,     __ATOMIC_RELAXED, __HIP_MEMORY_SCOPE_AGENT);
                hv[s][1] = __hip_atomic_load(hr + s * 8 + 1, __ATOMIC_RELAXED, __HIP_MEMORY_SCOPE_AGENT);
            }
            #pragma unroll
            for (int g = 0; g < 4; ++g) {
                u64 nv[8][2];
                if (g < 3) {
                    #pragma unroll
                    for (int s = 0; s < 8; ++s) {
                        const int sn = (g + 1) * 8 + s;
                        nv[s][0] = __hip_atomic_load(hr + sn * 8,     __ATOMIC_RELAXED, __HIP_MEMORY_SCOPE_AGENT);
                        nv[s][1] = __hip_atomic_load(hr + sn * 8 + 1, __ATOMIC_RELAXED, __HIP_MEMORY_SCOPE_AGENT);
                    }
                }
                #pragma unroll
                for (int s = 0; s < 8; ++s) {
                    const int sg = g * 8 + s;
                    union { u64 u[2]; bf16x8 v; } hf;
                    hf.u[0] = hv[s][0]; hf.u[1] = hv[s][1];
                    const bf16x8 b0 = *(const bf16x8*)(wl + 16384 + sg * 1024);
                    const bf16x8 b1 = *(const bf16x8*)(wl + 16384 + sg * 1024 + 128);
                    acc[0][sg & 1] = __builtin_amdgcn_mfma_f32_16x16x32_bf16(hf.v, b0, acc[0][sg & 1], 0, 0, 0);
                    acc[1][sg & 1] = __builtin_amdgcn_mfma_f32_16x16x32_bf16(hf.v, b1, acc[1][sg & 1], 0, 0, 0);
                }
                if (g < 3) {
                    #pragma unroll
                    for (int s = 0; s < 8; ++s) { hv[s][0] = nv[s][0]; hv[s][1] = nv[s][1]; }
                }
            }
        }
        const floatx4 av0 = acc[0][0] + acc[0][1];
        const floatx4 av1 = acc[1][0] + acc[1][1];

        // ---- transpose C via LDS ----
        #pragma unroll
        for (int r = 0; r < 4; ++r) {
            G[wid * 16 + q * 4 + r][cm]      = av0[r];
            G[wid * 16 + q * 4 + r][16 + cm] = av1[r];
        }
        __syncthreads();

        // ---- fused cell update: 2 (b,j) elems per thread ----
        const float4 g0 = *(const float4*)&G[eb][p * 8];
        const float4 g1 = *(const float4*)&G[eb][p * 8 + 4];
        const float i0 = 1.f / (1.f + expf(-(g0.x + bias0.x)));
        const float f0 = 1.f / (1.f + expf(-(g0.y + bias0.y)));
        const float o0 = 1.f / (1.f + expf(-(g0.z + bias0.z)));
        const float t0 = tanhf(g0.w + bias0.w);
        const float i1 = 1.f / (1.f + expf(-(g1.x + bias1.x)));
        const float f1 = 1.f / (1.f + expf(-(g1.y + bias1.y)));
        const float o1 = 1.f / (1.f + expf(-(g1.z + bias1.z)));
        const float t1 = tanhf(g1.w + bias1.w);
        c0 = f0 * c0 + i0 * t0;
        c1 = f1 * c1 + i1 * t1;
        const float hv0 = o0 * tanhf(c0);
        const float hv1 = o1 * tanhf(c1);
        const int hi = eb * H + jbase;
        union { __bf16 h2[2]; unsigned u; } hp;
        hp.h2[0] = (__bf16)hv0; hp.h2[1] = (__bf16)hv1;
        __hip_atomic_store((unsigned*)&hnxt[hi], hp.u, __ATOMIC_RELAXED,
                           __HIP_MEMORY_SCOPE_AGENT);   // write-through publish
        if (t == T - 1) { hfin[hi] = hv0; hfin[hi + 1] = hv1; }

        __syncthreads();  // G reads done + h stores vmcnt-drained before arrive

        // ---- arrive (relaxed tree), then overlap t+1's x-part ----
        if (tid == 0) {
            const int g = blockIdx.x >> 4;
            const unsigned old = __hip_atomic_fetch_add(&bar->grp[g][0], 1u,
                                    __ATOMIC_RELAXED, __HIP_MEMORY_SCOPE_AGENT);
            if (old == 16u * (unsigned)(t + 1) - 1u) {
                const unsigned r = __hip_atomic_fetch_add(&bar->root, 1u,
                                    __ATOMIC_RELAXED, __HIP_MEMORY_SCOPE_AGENT);
                if (r == 8u * (unsigned)(t + 1) - 1u) {
                    __hip_atomic_store(&bar->flag, (unsigned)(t + 1),
                                       __ATOMIC_RELAXED, __HIP_MEMORY_SCOPE_AGENT);
                }
            }
        }
        if (t + 1 < T) do_xpart(t + 1);
    }
}

// out[b,o] = h[b,:] . Why[o,:] + bhy[o]
__global__ __launch_bounds__(256) void out_gemm(
    const float* __restrict__ h, const float* __restrict__ Why,
    const float* __restrict__ bhy, float* __restrict__ out)
{
    const int idx = blockIdx.x * 256 + threadIdx.x;
    if (idx >= B * O) return;
    const int b = idx / O;
    const int o = idx % O;
    const float4* hv = (const float4*)&h[(size_t)b * H];
    const float4* wv = (const float4*)&Why[(size_t)o * H];
    float s = 0.f;
    #pragma unroll 4
    for (int k = 0; k < H / 4; ++k) {
        const float4 a = hv[k];
        const float4 w = wv[k];
        s += a.x * w.x + a.y * w.y + a.z * w.z + a.w * w.w;
    }
    out[idx] = s + bhy[o];
}

extern "C" void kernel_launch(void* const* d_in, const int* in_sizes, int n_in,
                              void* d_out, int out_size, void* d_ws, size_t ws_size,
                              hipStream_t stream) {
    const float* x   = (const float*)d_in[0];
    const float* Wx  = (const float*)d_in[1];
    const float* bx  = (const float*)d_in[2];
    const float* Wh  = (const float*)d_in[3];
    const float* bh  = (const float*)d_in[4];
    const float* Why = (const float*)d_in[5];
    const float* bhy = (const float*)d_in[6];
    float* out = (float*)d_out;

    // ws layout (12,863,488 B total):
    // Wc 12,582,912 | bias 16,384 | hb0 131,072 | bar 2,048 | hb1 131,072
    // hfin (256 KB fp32) aliases Wc[0:262144) — Wc only read during the
    // one-time LDS stage, 511 barriers before any t=T-1 write. Safe.
    char* ws = (char*)d_ws;
    __bf16* Wc   = (__bf16*)ws;
    float*  bias = (float*)(ws + 12582912);
    __bf16* hb0  = (__bf16*)(ws + 12599296);
    GBar*   bar  = (GBar*)  (ws + 12730368);
    __bf16* hb1  = (__bf16*)(ws + 12732416);
    float*  hfin = (float*)ws;

    hipMemsetAsync(ws + 12599296, 0, 131072 + 2048, stream);  // hb0 + bar
    convert_w<<<3072, 256, 0, stream>>>(Wx, Wh, Wc);
    make_bias<<<16, 256, 0, stream>>>(bx, bh, bias);

    lstm_persistent<<<NBLK, 256, 0, stream>>>(x, Wc, bias, hb0, hb1, hfin, bar);

    out_gemm<<<(B * O + 255) / 256, 256, 0, stream>>>(hfin, Why, bhy, out);
}

// Round 10
// 5973.619 us; speedup vs baseline: 1.7347x; 1.2170x over previous
//
#include <hip/hip_runtime.h>
#include <hip/hip_bf16.h>
#include <math.h>

// Problem constants: T=512, B=64, D=512, H=1024, O=512
constexpr int T = 512;
constexpr int B = 64;
constexpr int D = 512;
constexpr int H = 1024;
constexpr int O = 512;
constexpr int NBLK = 128;          // persistent blocks, 1 per CU (96KB LDS)
constexpr int COLS = 32;           // gate-cols per block (8 hidden j's x 4 gates)
constexpr int KCH  = (D + H) / 8;  // 192 k-chunks of 8 elems

typedef __attribute__((ext_vector_type(8))) __bf16 bf16x8;
typedef __attribute__((ext_vector_type(4))) float  floatx4;
typedef unsigned long long u64;

// Tree barrier: 8 group counters (16 arrivals) -> root (8) -> flag. All relaxed;
// h visibility is physical (write-through stores, cache-bypass reads).
struct GBar {
    unsigned grp[8][32];
    unsigned root; unsigned p0[31];
    unsigned flag; unsigned p1[31];
};

// ---------------------------------------------------------------------------
// W' bf16, strip-major: Wc[strip(128)][kchunk(192)][nl(32)][8]; col reorder
// n = j*4+g. k<512 from Wx[g*H+j][k], else Wh[g*H+j][k-512].
// ---------------------------------------------------------------------------
__global__ __launch_bounds__(256) void convert_w(
    const float* __restrict__ Wx, const float* __restrict__ Wh,
    __bf16* __restrict__ Wc)
{
    const int id = blockIdx.x * 256 + threadIdx.x;   // 128*192*32 = 786432
    if (id >= NBLK * KCH * COLS) return;
    const int nl     = id & 31;
    const int kchunk = (id >> 5) % KCH;
    const int strip  = id / (KCH * COLS);
    const int n = strip * COLS + nl;
    const int j = n >> 2, g = n & 3;
    const int k0 = kchunk * 8;
    const float* src = (k0 < D) ? &Wx[(size_t)(g * H + j) * D + k0]
                                : &Wh[(size_t)(g * H + j) * H + (k0 - D)];
    const float4 a = *(const float4*)src;
    const float4 b = *(const float4*)(src + 4);
    __bf16 t8[8] = {(__bf16)a.x,(__bf16)a.y,(__bf16)a.z,(__bf16)a.w,
                    (__bf16)b.x,(__bf16)b.y,(__bf16)b.z,(__bf16)b.w};
    *(uint4*)&Wc[(size_t)id * 8] = *(uint4*)t8;
}

__global__ __launch_bounds__(256) void make_bias(
    const float* __restrict__ bx, const float* __restrict__ bh,
    float* __restrict__ bias)
{
    const int n = blockIdx.x * 256 + threadIdx.x;
    if (n < 4 * H) {
        const int j = n >> 2, g = n & 3;
        bias[n] = bx[g * H + j] + bh[g * H + j];
    }
}

// ---------------------------------------------------------------------------
// Persistent LSTM, round 10: identical to round 9 except the asm outputs are
// EARLY-CLOBBER ("=&v"). Round 9 crashed because plain "=v" let the register
// allocator overlap the address input with load destinations: an early-
// returning load overwrote the address pair while later loads still read it
// -> wild address -> fault. "&" forces disjoint registers.
//
// Theory under test (rounds 8-10): the ~10us/step floor is per-lane 8B
// atomic-load requests at the TCC (~2.1M/step); wide plain sc0 sc1 dwordx4
// loads coalesce into dense 64B sectors (~8x fewer requests).
// ---------------------------------------------------------------------------
__global__ __launch_bounds__(256, 1) void lstm_persistent(
    const float* __restrict__ x,     // [T,B,D] fp32
    const __bf16* __restrict__ Wc,   // strip-major bf16 (read once at start)
    const float* __restrict__ bias,  // [4096] reordered
    __bf16* __restrict__ hb0,        // [B,H] bf16 ping
    __bf16* __restrict__ hb1,        // [B,H] bf16 pong
    float* __restrict__ hfin,        // [B,H] fp32 final h (aliases Wc head)
    GBar* bar)
{
    __shared__ __attribute__((aligned(16))) __bf16 wlds[KCH * COLS * 8]; // 96 KB
    __shared__ __attribute__((aligned(16))) float  G[64][COLS + 4];      // 9.2 KB

    const int tid  = threadIdx.x;
    const int wid  = tid >> 6;     // wave id == m-tile (16 batch rows)
    const int lane = tid & 63;
    const int cm   = lane & 15;
    const int q    = lane >> 4;
    const int n0   = blockIdx.x * COLS;

    // ---- one-time: W strip -> LDS (6144 x 16B contiguous) ----
    {
        const uint4* wsrc = (const uint4*)(Wc + (size_t)blockIdx.x * KCH * COLS * 8);
        uint4* wdst = (uint4*)wlds;
        for (int i = tid; i < KCH * COLS; i += 256) wdst[i] = wsrc[i];
    }
    // epilogue mapping: thread owns (b=eb, j=jbase,jbase+1); c in registers
    const int eb = tid >> 2;
    const int p  = tid & 3;
    const int jbase = (n0 >> 2) + p * 2;
    const float4 bias0 = *(const float4*)&bias[n0 + p * 8];
    const float4 bias1 = *(const float4*)&bias[n0 + p * 8 + 4];
    float c0 = 0.f, c1 = 0.f;
    __syncthreads();

    const float* xrow = x + (size_t)(wid * 16 + cm) * D + q * 8;
    const int    hoff = (wid * 16 + cm) * H + q * 8;
    const __bf16* wl  = wlds + (q * 32 + cm) * 8;  // + s*1024 (+128 for strip1)

    floatx4 acc[2][2];  // [strip][k-parity]

    // x-part of step tt: K=0..511, prefetch pipeline (round-7, unchanged)
    auto do_xpart = [&](int tt) {
        acc[0][0] = (floatx4){0,0,0,0}; acc[0][1] = (floatx4){0,0,0,0};
        acc[1][0] = (floatx4){0,0,0,0}; acc[1][1] = (floatx4){0,0,0,0};
        const float* xr = xrow + (size_t)tt * (B * D);
        float4 cur[8][2];
        #pragma unroll
        for (int s = 0; s < 8; ++s) {
            cur[s][0] = *(const float4*)(xr + s * 32);
            cur[s][1] = *(const float4*)(xr + s * 32 + 4);
        }
        #pragma unroll
        for (int g = 0; g < 2; ++g) {
            float4 nxt[8][2];
            if (g == 0) {
                #pragma unroll
                for (int s = 0; s < 8; ++s) {
                    nxt[s][0] = *(const float4*)(xr + (8 + s) * 32);
                    nxt[s][1] = *(const float4*)(xr + (8 + s) * 32 + 4);
                }
            }
            #pragma unroll
            for (int s = 0; s < 8; ++s) {
                const int sg = g * 8 + s;
                const float4 a0 = cur[s][0], a1 = cur[s][1];
                const bf16x8 af = {(__bf16)a0.x,(__bf16)a0.y,(__bf16)a0.z,(__bf16)a0.w,
                                   (__bf16)a1.x,(__bf16)a1.y,(__bf16)a1.z,(__bf16)a1.w};
                const bf16x8 b0 = *(const bf16x8*)(wl + sg * 1024);
                const bf16x8 b1 = *(const bf16x8*)(wl + sg * 1024 + 128);
                acc[0][sg & 1] = __builtin_amdgcn_mfma_f32_16x16x32_bf16(af, b0, acc[0][sg & 1], 0, 0, 0);
                acc[1][sg & 1] = __builtin_amdgcn_mfma_f32_16x16x32_bf16(af, b1, acc[1][sg & 1], 0, 0, 0);
            }
            if (g == 0) {
                #pragma unroll
                for (int s = 0; s < 8; ++s) { cur[s][0] = nxt[s][0]; cur[s][1] = nxt[s][1]; }
            }
        }
    };

    do_xpart(0);

    for (int t = 0; t < T; ++t) {
        const __bf16* hcur = (t & 1) ? hb1 : hb0;
        __bf16*       hnxt = (t & 1) ? hb0 : hb1;

        // ---- wait for step t-1's h ----
        if (t > 0) {
            if (tid == 0) {
                while (__hip_atomic_load(&bar->flag, __ATOMIC_RELAXED,
                                         __HIP_MEMORY_SCOPE_AGENT) < (unsigned)t)
                    __builtin_amdgcn_s_sleep(1);
            }
            __syncthreads();
        }

        // ---- h-part: K=512..1535. 32 coherent dwordx4 loads in ONE asm
        //      block + vmcnt(0); then consume (64 MFMAs from registers) ----
        {
            const __bf16* hbase = hcur + hoff;   // per-lane, 16B aligned
            uint4 hv[32];
            asm volatile(
                "global_load_dwordx4 %0, %32, off sc0 sc1\n\t"
                "global_load_dwordx4 %1, %32, off offset:64 sc0 sc1\n\t"
                "global_load_dwordx4 %2, %32, off offset:128 sc0 sc1\n\t"
                "global_load_dwordx4 %3, %32, off offset:192 sc0 sc1\n\t"
                "global_load_dwordx4 %4, %32, off offset:256 sc0 sc1\n\t"
                "global_load_dwordx4 %5, %32, off offset:320 sc0 sc1\n\t"
                "global_load_dwordx4 %6, %32, off offset:384 sc0 sc1\n\t"
                "global_load_dwordx4 %7, %32, off offset:448 sc0 sc1\n\t"
                "global_load_dwordx4 %8, %32, off offset:512 sc0 sc1\n\t"
                "global_load_dwordx4 %9, %32, off offset:576 sc0 sc1\n\t"
                "global_load_dwordx4 %10, %32, off offset:640 sc0 sc1\n\t"
                "global_load_dwordx4 %11, %32, off offset:704 sc0 sc1\n\t"
                "global_load_dwordx4 %12, %32, off offset:768 sc0 sc1\n\t"
                "global_load_dwordx4 %13, %32, off offset:832 sc0 sc1\n\t"
                "global_load_dwordx4 %14, %32, off offset:896 sc0 sc1\n\t"
                "global_load_dwordx4 %15, %32, off offset:960 sc0 sc1\n\t"
                "global_load_dwordx4 %16, %32, off offset:1024 sc0 sc1\n\t"
                "global_load_dwordx4 %17, %32, off offset:1088 sc0 sc1\n\t"
                "global_load_dwordx4 %18, %32, off offset:1152 sc0 sc1\n\t"
                "global_load_dwordx4 %19, %32, off offset:1216 sc0 sc1\n\t"
                "global_load_dwordx4 %20, %32, off offset:1280 sc0 sc1\n\t"
                "global_load_dwordx4 %21, %32, off offset:1344 sc0 sc1\n\t"
                "global_load_dwordx4 %22, %32, off offset:1408 sc0 sc1\n\t"
                "global_load_dwordx4 %23, %32, off offset:1472 sc0 sc1\n\t"
                "global_load_dwordx4 %24, %32, off offset:1536 sc0 sc1\n\t"
                "global_load_dwordx4 %25, %32, off offset:1600 sc0 sc1\n\t"
                "global_load_dwordx4 %26, %32, off offset:1664 sc0 sc1\n\t"
                "global_load_dwordx4 %27, %32, off offset:1728 sc0 sc1\n\t"
                "global_load_dwordx4 %28, %32, off offset:1792 sc0 sc1\n\t"
                "global_load_dwordx4 %29, %32, off offset:1856 sc0 sc1\n\t"
                "global_load_dwordx4 %30, %32, off offset:1920 sc0 sc1\n\t"
                "global_load_dwordx4 %31, %32, off offset:1984 sc0 sc1\n\t"
                "s_waitcnt vmcnt(0)"
                : "=&v"(hv[0]),  "=&v"(hv[1]),  "=&v"(hv[2]),  "=&v"(hv[3]),
                  "=&v"(hv[4]),  "=&v"(hv[5]),  "=&v"(hv[6]),  "=&v"(hv[7]),
                  "=&v"(hv[8]),  "=&v"(hv[9]),  "=&v"(hv[10]), "=&v"(hv[11]),
                  "=&v"(hv[12]), "=&v"(hv[13]), "=&v"(hv[14]), "=&v"(hv[15]),
                  "=&v"(hv[16]), "=&v"(hv[17]), "=&v"(hv[18]), "=&v"(hv[19]),
                  "=&v"(hv[20]), "=&v"(hv[21]), "=&v"(hv[22]), "=&v"(hv[23]),
                  "=&v"(hv[24]), "=&v"(hv[25]), "=&v"(hv[26]), "=&v"(hv[27]),
                  "=&v"(hv[28]), "=&v"(hv[29]), "=&v"(hv[30]), "=&v"(hv[31])
                : "v"(hbase)
                : "memory");
            #pragma unroll
            for (int sg = 0; sg < 32; ++sg) {
                union { uint4 u; bf16x8 v; } hf; hf.u = hv[sg];
                const bf16x8 b0 = *(const bf16x8*)(wl + 16384 + sg * 1024);
                const bf16x8 b1 = *(const bf16x8*)(wl + 16384 + sg * 1024 + 128);
                acc[0][sg & 1] = __builtin_amdgcn_mfma_f32_16x16x32_bf16(hf.v, b0, acc[0][sg & 1], 0, 0, 0);
                acc[1][sg & 1] = __builtin_amdgcn_mfma_f32_16x16x32_bf16(hf.v, b1, acc[1][sg & 1], 0, 0, 0);
            }
        }
        const floatx4 av0 = acc[0][0] + acc[0][1];
        const floatx4 av1 = acc[1][0] + acc[1][1];

        // ---- transpose C via LDS ----
        #pragma unroll
        for (int r = 0; r < 4; ++r) {
            G[wid * 16 + q * 4 + r][cm]      = av0[r];
            G[wid * 16 + q * 4 + r][16 + cm] = av1[r];
        }
        __syncthreads();

        // ---- fused cell update: 2 (b,j) elems per thread ----
        const float4 g0 = *(const float4*)&G[eb][p * 8];
        const float4 g1 = *(const float4*)&G[eb][p * 8 + 4];
        const float i0 = 1.f / (1.f + expf(-(g0.x + bias0.x)));
        const float f0 = 1.f / (1.f + expf(-(g0.y + bias0.y)));
        const float o0 = 1.f / (1.f + expf(-(g0.z + bias0.z)));
        const float t0 = tanhf(g0.w + bias0.w);
        const float i1 = 1.f / (1.f + expf(-(g1.x + bias1.x)));
        const float f1 = 1.f / (1.f + expf(-(g1.y + bias1.y)));
        const float o1 = 1.f / (1.f + expf(-(g1.z + bias1.z)));
        const float t1 = tanhf(g1.w + bias1.w);
        c0 = f0 * c0 + i0 * t0;
        c1 = f1 * c1 + i1 * t1;
        const float hv0 = o0 * tanhf(c0);
        const float hv1 = o1 * tanhf(c1);
        const int hi = eb * H + jbase;
        union { __bf16 h2[2]; unsigned u; } hp;
        hp.h2[0] = (__bf16)hv0; hp.h2[1] = (__bf16)hv1;
        __hip_atomic_store((unsigned*)&hnxt[hi], hp.u, __ATOMIC_RELAXED,
                           __HIP_MEMORY_SCOPE_AGENT);   // write-through publish
        if (t == T - 1) { hfin[hi] = hv0; hfin[hi + 1] = hv1; }

        __syncthreads();  // G reads done + h stores vmcnt-drained before arrive

        // ---- arrive (relaxed tree), then overlap t+1's x-part ----
        if (tid == 0) {
            const int g = blockIdx.x >> 4;
            const unsigned old = __hip_atomic_fetch_add(&bar->grp[g][0], 1u,
                                    __ATOMIC_RELAXED, __HIP_MEMORY_SCOPE_AGENT);
            if (old == 16u * (unsigned)(t + 1) - 1u) {
                const unsigned r = __hip_atomic_fetch_add(&bar->root, 1u,
                                    __ATOMIC_RELAXED, __HIP_MEMORY_SCOPE_AGENT);
                if (r == 8u * (unsigned)(t + 1) - 1u) {
                    __hip_atomic_store(&bar->flag, (unsigned)(t + 1),
                                       __ATOMIC_RELAXED, __HIP_MEMORY_SCOPE_AGENT);
                }
            }
        }
        if (t + 1 < T) do_xpart(t + 1);
    }
}

// out[b,o] = h[b,:] . Why[o,:] + bhy[o]
__global__ __launch_bounds__(256) void out_gemm(
    const float* __restrict__ h, const float* __restrict__ Why,
    const float* __restrict__ bhy, float* __restrict__ out)
{
    const int idx = blockIdx.x * 256 + threadIdx.x;
    if (idx >= B * O) return;
    const int b = idx / O;
    const int o = idx % O;
    const float4* hv = (const float4*)&h[(size_t)b * H];
    const float4* wv = (const float4*)&Why[(size_t)o * H];
    float s = 0.f;
    #pragma unroll 4
    for (int k = 0; k < H / 4; ++k) {
        const float4 a = hv[k];
        const float4 w = wv[k];
        s += a.x * w.x + a.y * w.y + a.z * w.z + a.w * w.w;
    }
    out[idx] = s + bhy[o];
}

extern "C" void kernel_launch(void* const* d_in, const int* in_sizes, int n_in,
                              void* d_out, int out_size, void* d_ws, size_t ws_size,
                              hipStream_t stream) {
    const float* x   = (const float*)d_in[0];
    const float* Wx  = (const float*)d_in[1];
    const float* bx  = (const float*)d_in[2];
    const float* Wh  = (const float*)d_in[3];
    const float* bh  = (const float*)d_in[4];
    const float* Why = (const float*)d_in[5];
    const float* bhy = (const float*)d_in[6];
    float* out = (float*)d_out;

    // ws layout (12,863,488 B total):
    // Wc 12,582,912 | bias 16,384 | hb0 131,072 | bar 2,048 | hb1 131,072
    // hfin (256 KB fp32) aliases Wc[0:262144) — Wc only read during the
    // one-time LDS stage, 511 barriers before any t=T-1 write. Safe.
    char* ws = (char*)d_ws;
    __bf16* Wc   = (__bf16*)ws;
    float*  bias = (float*)(ws + 12582912);
    __bf16* hb0  = (__bf16*)(ws + 12599296);
    GBar*   bar  = (GBar*)  (ws + 12730368);
    __bf16* hb1  = (__bf16*)(ws + 12732416);
    float*  hfin = (float*)ws;

    (void)hipMemsetAsync(ws + 12599296, 0, 131072 + 2048, stream);  // hb0 + bar
    convert_w<<<3072, 256, 0, stream>>>(Wx, Wh, Wc);
    make_bias<<<16, 256, 0, stream>>>(bx, bh, bias);

    lstm_persistent<<<NBLK, 256, 0, stream>>>(x, Wc, bias, hb0, hb1, hfin, bar);

    out_gemm<<<(B * O + 255) / 256, 256, 0, stream>>>(hfin, Why, bhy, out);
}

// Round 11
// 4481.581 us; speedup vs baseline: 2.3122x; 1.3329x over previous
//
#include <hip/hip_runtime.h>
#include <hip/hip_bf16.h>
#include <math.h>

// Problem constants: T=512, B=64, D=512, H=1024, O=512
constexpr int T = 512;
constexpr int B = 64;
constexpr int D = 512;
constexpr int H = 1024;
constexpr int O = 512;
constexpr int NBLK = 128;          // persistent blocks, 1 per CU (96KB LDS)
constexpr int COLS = 32;           // gate-cols per block (8 hidden j's x 4 gates)
constexpr int KCH  = (D + H) / 8;  // 192 k-chunks of 8 elems

typedef __attribute__((ext_vector_type(8))) __bf16 bf16x8;
typedef __attribute__((ext_vector_type(4))) float  floatx4;
typedef unsigned long long u64;

// Tree barrier with FAN-OUT flags: 8 group counters (16 arrivals) -> root (8)
// -> root leader stores 8 per-group flag lines; each group polls its own line
// (round-11: cuts 128-reader contention on one line by 16x). All relaxed;
// h visibility is physical (write-through stores, cache-bypass reads).
struct GBar {
    unsigned grp[8][32];     // arrival counters, one 128B line each
    unsigned root; unsigned p0[31];
    unsigned gflag[8][32];   // per-group broadcast flags, one line each
};

// ---------------------------------------------------------------------------
// W' bf16, strip-major: Wc[strip(128)][kchunk(192)][nl(32)][8]; col reorder
// n = j*4+g. k<512 from Wx[g*H+j][k], else Wh[g*H+j][k-512].
// ---------------------------------------------------------------------------
__global__ __launch_bounds__(256) void convert_w(
    const float* __restrict__ Wx, const float* __restrict__ Wh,
    __bf16* __restrict__ Wc)
{
    const int id = blockIdx.x * 256 + threadIdx.x;   // 128*192*32 = 786432
    if (id >= NBLK * KCH * COLS) return;
    const int nl     = id & 31;
    const int kchunk = (id >> 5) % KCH;
    const int strip  = id / (KCH * COLS);
    const int n = strip * COLS + nl;
    const int j = n >> 2, g = n & 3;
    const int k0 = kchunk * 8;
    const float* src = (k0 < D) ? &Wx[(size_t)(g * H + j) * D + k0]
                                : &Wh[(size_t)(g * H + j) * H + (k0 - D)];
    const float4 a = *(const float4*)src;
    const float4 b = *(const float4*)(src + 4);
    __bf16 t8[8] = {(__bf16)a.x,(__bf16)a.y,(__bf16)a.z,(__bf16)a.w,
                    (__bf16)b.x,(__bf16)b.y,(__bf16)b.z,(__bf16)b.w};
    *(uint4*)&Wc[(size_t)id * 8] = *(uint4*)t8;
}

__global__ __launch_bounds__(256) void make_bias(
    const float* __restrict__ bx, const float* __restrict__ bh,
    float* __restrict__ bias)
{
    const int n = blockIdx.x * 256 + threadIdx.x;
    if (n < 4 * H) {
        const int j = n >> 2, g = n & 3;
        bias[n] = bx[g * H + j] + bh[g * H + j];
    }
}

// ---------------------------------------------------------------------------
// Persistent LSTM, round 11 = round 10 core (verified) + three shavings:
//  (a) fan-out flags: root leader writes 8 per-group flag lines.
//  (b) x loads for t+1 issued during the epilogue (before sync1): their L2
//      RTT hides under the cell-update phase.
//  (c) x MFMAs for t+1 run after the arrive, consuming already-loaded
//      registers inside the barrier-propagation shadow.
// h broadcast stays: 32 wide sc0 sc1 dwordx4 loads in one early-clobber asm
// block + vmcnt(0).
// ---------------------------------------------------------------------------
__global__ __launch_bounds__(256, 1) void lstm_persistent(
    const float* __restrict__ x,     // [T,B,D] fp32
    const __bf16* __restrict__ Wc,   // strip-major bf16 (read once at start)
    const float* __restrict__ bias,  // [4096] reordered
    __bf16* __restrict__ hb0,        // [B,H] bf16 ping
    __bf16* __restrict__ hb1,        // [B,H] bf16 pong
    float* __restrict__ hfin,        // [B,H] fp32 final h (aliases Wc head)
    GBar* bar)
{
    __shared__ __attribute__((aligned(16))) __bf16 wlds[KCH * COLS * 8]; // 96 KB
    __shared__ __attribute__((aligned(16))) float  G[64][COLS + 4];      // 9.2 KB

    const int tid  = threadIdx.x;
    const int wid  = tid >> 6;     // wave id == m-tile (16 batch rows)
    const int lane = tid & 63;
    const int cm   = lane & 15;
    const int q    = lane >> 4;
    const int n0   = blockIdx.x * COLS;

    // ---- one-time: W strip -> LDS (6144 x 16B contiguous) ----
    {
        const uint4* wsrc = (const uint4*)(Wc + (size_t)blockIdx.x * KCH * COLS * 8);
        uint4* wdst = (uint4*)wlds;
        for (int i = tid; i < KCH * COLS; i += 256) wdst[i] = wsrc[i];
    }
    // epilogue mapping: thread owns (b=eb, j=jbase,jbase+1); c in registers
    const int eb = tid >> 2;
    const int p  = tid & 3;
    const int jbase = (n0 >> 2) + p * 2;
    const float4 bias0 = *(const float4*)&bias[n0 + p * 8];
    const float4 bias1 = *(const float4*)&bias[n0 + p * 8 + 4];
    float c0 = 0.f, c1 = 0.f;
    __syncthreads();

    const float* xrow = x + (size_t)(wid * 16 + cm) * D + q * 8;
    const int    hoff = (wid * 16 + cm) * H + q * 8;
    const __bf16* wl  = wlds + (q * 32 + cm) * 8;  // + s*1024 (+128 for strip1)

    floatx4 acc[2][2];  // [strip][k-parity]
    float4  xcur[16][2];   // prefetched x_t fragments (128 VGPRs, dead in h-part)

    auto loadx = [&](int tt) {
        const float* xr = xrow + (size_t)tt * (B * D);
        #pragma unroll
        for (int s = 0; s < 16; ++s) {
            xcur[s][0] = *(const float4*)(xr + s * 32);
            xcur[s][1] = *(const float4*)(xr + s * 32 + 4);
        }
    };
    // zero acc, run the 32 x MFMAs from registers (K = 0..511)
    auto xmfma = [&]() {
        acc[0][0] = (floatx4){0,0,0,0}; acc[0][1] = (floatx4){0,0,0,0};
        acc[1][0] = (floatx4){0,0,0,0}; acc[1][1] = (floatx4){0,0,0,0};
        #pragma unroll
        for (int s = 0; s < 16; ++s) {
            const float4 a0 = xcur[s][0], a1 = xcur[s][1];
            const bf16x8 af = {(__bf16)a0.x,(__bf16)a0.y,(__bf16)a0.z,(__bf16)a0.w,
                               (__bf16)a1.x,(__bf16)a1.y,(__bf16)a1.z,(__bf16)a1.w};
            const bf16x8 b0 = *(const bf16x8*)(wl + s * 1024);
            const bf16x8 b1 = *(const bf16x8*)(wl + s * 1024 + 128);
            acc[0][s & 1] = __builtin_amdgcn_mfma_f32_16x16x32_bf16(af, b0, acc[0][s & 1], 0, 0, 0);
            acc[1][s & 1] = __builtin_amdgcn_mfma_f32_16x16x32_bf16(af, b1, acc[1][s & 1], 0, 0, 0);
        }
    };

    loadx(0);
    xmfma();

    const int grp = blockIdx.x >> 4;

    for (int t = 0; t < T; ++t) {
        const __bf16* hcur = (t & 1) ? hb1 : hb0;
        __bf16*       hnxt = (t & 1) ? hb0 : hb1;

        // ---- wait for step t-1's h (poll own group's flag line) ----
        if (t > 0) {
            if (tid == 0) {
                while (__hip_atomic_load(&bar->gflag[grp][0], __ATOMIC_RELAXED,
                                         __HIP_MEMORY_SCOPE_AGENT) < (unsigned)t)
                    __builtin_amdgcn_s_sleep(1);
            }
            __syncthreads();
        }

        // ---- h-part: K=512..1535. 32 coherent dwordx4 loads in ONE asm
        //      block + vmcnt(0); then consume (64 MFMAs from registers) ----
        {
            const __bf16* hbase = hcur + hoff;   // per-lane, 16B aligned
            uint4 hv[32];
            asm volatile(
                "global_load_dwordx4 %0, %32, off sc0 sc1\n\t"
                "global_load_dwordx4 %1, %32, off offset:64 sc0 sc1\n\t"
                "global_load_dwordx4 %2, %32, off offset:128 sc0 sc1\n\t"
                "global_load_dwordx4 %3, %32, off offset:192 sc0 sc1\n\t"
                "global_load_dwordx4 %4, %32, off offset:256 sc0 sc1\n\t"
                "global_load_dwordx4 %5, %32, off offset:320 sc0 sc1\n\t"
                "global_load_dwordx4 %6, %32, off offset:384 sc0 sc1\n\t"
                "global_load_dwordx4 %7, %32, off offset:448 sc0 sc1\n\t"
                "global_load_dwordx4 %8, %32, off offset:512 sc0 sc1\n\t"
                "global_load_dwordx4 %9, %32, off offset:576 sc0 sc1\n\t"
                "global_load_dwordx4 %10, %32, off offset:640 sc0 sc1\n\t"
                "global_load_dwordx4 %11, %32, off offset:704 sc0 sc1\n\t"
                "global_load_dwordx4 %12, %32, off offset:768 sc0 sc1\n\t"
                "global_load_dwordx4 %13, %32, off offset:832 sc0 sc1\n\t"
                "global_load_dwordx4 %14, %32, off offset:896 sc0 sc1\n\t"
                "global_load_dwordx4 %15, %32, off offset:960 sc0 sc1\n\t"
                "global_load_dwordx4 %16, %32, off offset:1024 sc0 sc1\n\t"
                "global_load_dwordx4 %17, %32, off offset:1088 sc0 sc1\n\t"
                "global_load_dwordx4 %18, %32, off offset:1152 sc0 sc1\n\t"
                "global_load_dwordx4 %19, %32, off offset:1216 sc0 sc1\n\t"
                "global_load_dwordx4 %20, %32, off offset:1280 sc0 sc1\n\t"
                "global_load_dwordx4 %21, %32, off offset:1344 sc0 sc1\n\t"
                "global_load_dwordx4 %22, %32, off offset:1408 sc0 sc1\n\t"
                "global_load_dwordx4 %23, %32, off offset:1472 sc0 sc1\n\t"
                "global_load_dwordx4 %24, %32, off offset:1536 sc0 sc1\n\t"
                "global_load_dwordx4 %25, %32, off offset:1600 sc0 sc1\n\t"
                "global_load_dwordx4 %26, %32, off offset:1664 sc0 sc1\n\t"
                "global_load_dwordx4 %27, %32, off offset:1728 sc0 sc1\n\t"
                "global_load_dwordx4 %28, %32, off offset:1792 sc0 sc1\n\t"
                "global_load_dwordx4 %29, %32, off offset:1856 sc0 sc1\n\t"
                "global_load_dwordx4 %30, %32, off offset:1920 sc0 sc1\n\t"
                "global_load_dwordx4 %31, %32, off offset:1984 sc0 sc1\n\t"
                "s_waitcnt vmcnt(0)"
                : "=&v"(hv[0]),  "=&v"(hv[1]),  "=&v"(hv[2]),  "=&v"(hv[3]),
                  "=&v"(hv[4]),  "=&v"(hv[5]),  "=&v"(hv[6]),  "=&v"(hv[7]),
                  "=&v"(hv[8]),  "=&v"(hv[9]),  "=&v"(hv[10]), "=&v"(hv[11]),
                  "=&v"(hv[12]), "=&v"(hv[13]), "=&v"(hv[14]), "=&v"(hv[15]),
                  "=&v"(hv[16]), "=&v"(hv[17]), "=&v"(hv[18]), "=&v"(hv[19]),
                  "=&v"(hv[20]), "=&v"(hv[21]), "=&v"(hv[22]), "=&v"(hv[23]),
                  "=&v"(hv[24]), "=&v"(hv[25]), "=&v"(hv[26]), "=&v"(hv[27]),
                  "=&v"(hv[28]), "=&v"(hv[29]), "=&v"(hv[30]), "=&v"(hv[31])
                : "v"(hbase)
                : "memory");
            #pragma unroll
            for (int sg = 0; sg < 32; ++sg) {
                union { uint4 u; bf16x8 v; } hf; hf.u = hv[sg];
                const bf16x8 b0 = *(const bf16x8*)(wl + 16384 + sg * 1024);
                const bf16x8 b1 = *(const bf16x8*)(wl + 16384 + sg * 1024 + 128);
                acc[0][sg & 1] = __builtin_amdgcn_mfma_f32_16x16x32_bf16(hf.v, b0, acc[0][sg & 1], 0, 0, 0);
                acc[1][sg & 1] = __builtin_amdgcn_mfma_f32_16x16x32_bf16(hf.v, b1, acc[1][sg & 1], 0, 0, 0);
            }
        }
        const floatx4 av0 = acc[0][0] + acc[0][1];
        const floatx4 av1 = acc[1][0] + acc[1][1];

        // ---- transpose C via LDS ----
        #pragma unroll
        for (int r = 0; r < 4; ++r) {
            G[wid * 16 + q * 4 + r][cm]      = av0[r];
            G[wid * 16 + q * 4 + r][16 + cm] = av1[r];
        }

        // ---- (b) prefetch x for t+1: L2 RTT hides under the epilogue ----
        if (t + 1 < T) loadx(t + 1);

        __syncthreads();

        // ---- fused cell update: 2 (b,j) elems per thread ----
        const float4 g0 = *(const float4*)&G[eb][p * 8];
        const float4 g1 = *(const float4*)&G[eb][p * 8 + 4];
        const float i0 = 1.f / (1.f + expf(-(g0.x + bias0.x)));
        const float f0 = 1.f / (1.f + expf(-(g0.y + bias0.y)));
        const float o0 = 1.f / (1.f + expf(-(g0.z + bias0.z)));
        const float t0 = tanhf(g0.w + bias0.w);
        const float i1 = 1.f / (1.f + expf(-(g1.x + bias1.x)));
        const float f1 = 1.f / (1.f + expf(-(g1.y + bias1.y)));
        const float o1 = 1.f / (1.f + expf(-(g1.z + bias1.z)));
        const float t1 = tanhf(g1.w + bias1.w);
        c0 = f0 * c0 + i0 * t0;
        c1 = f1 * c1 + i1 * t1;
        const float hv0 = o0 * tanhf(c0);
        const float hv1 = o1 * tanhf(c1);
        const int hi = eb * H + jbase;
        union { __bf16 h2[2]; unsigned u; } hp;
        hp.h2[0] = (__bf16)hv0; hp.h2[1] = (__bf16)hv1;
        __hip_atomic_store((unsigned*)&hnxt[hi], hp.u, __ATOMIC_RELAXED,
                           __HIP_MEMORY_SCOPE_AGENT);   // write-through publish
        if (t == T - 1) { hfin[hi] = hv0; hfin[hi + 1] = hv1; }

        __syncthreads();  // G reads done + h stores vmcnt-drained before arrive

        // ---- arrive ASAP (relaxed tree, fan-out flags) ----
        if (tid == 0) {
            const unsigned old = __hip_atomic_fetch_add(&bar->grp[grp][0], 1u,
                                    __ATOMIC_RELAXED, __HIP_MEMORY_SCOPE_AGENT);
            if (old == 16u * (unsigned)(t + 1) - 1u) {
                const unsigned r = __hip_atomic_fetch_add(&bar->root, 1u,
                                    __ATOMIC_RELAXED, __HIP_MEMORY_SCOPE_AGENT);
                if (r == 8u * (unsigned)(t + 1) - 1u) {
                    #pragma unroll
                    for (int k = 0; k < 8; ++k)
                        __hip_atomic_store(&bar->gflag[k][0], (unsigned)(t + 1),
                                           __ATOMIC_RELAXED, __HIP_MEMORY_SCOPE_AGENT);
                }
            }
        }
        // ---- (c) x MFMAs for t+1 in the barrier-propagation shadow ----
        if (t + 1 < T) xmfma();
    }
}

// out[b,o] = h[b,:] . Why[o,:] + bhy[o]
__global__ __launch_bounds__(256) void out_gemm(
    const float* __restrict__ h, const float* __restrict__ Why,
    const float* __restrict__ bhy, float* __restrict__ out)
{
    const int idx = blockIdx.x * 256 + threadIdx.x;
    if (idx >= B * O) return;
    const int b = idx / O;
    const int o = idx % O;
    const float4* hv = (const float4*)&h[(size_t)b * H];
    const float4* wv = (const float4*)&Why[(size_t)o * H];
    float s = 0.f;
    #pragma unroll 4
    for (int k = 0; k < H / 4; ++k) {
        const float4 a = hv[k];
        const float4 w = wv[k];
        s += a.x * w.x + a.y * w.y + a.z * w.z + a.w * w.w;
    }
    out[idx] = s + bhy[o];
}

extern "C" void kernel_launch(void* const* d_in, const int* in_sizes, int n_in,
                              void* d_out, int out_size, void* d_ws, size_t ws_size,
                              hipStream_t stream) {
    const float* x   = (const float*)d_in[0];
    const float* Wx  = (const float*)d_in[1];
    const float* bx  = (const float*)d_in[2];
    const float* Wh  = (const float*)d_in[3];
    const float* bh  = (const float*)d_in[4];
    const float* Why = (const float*)d_in[5];
    const float* bhy = (const float*)d_in[6];
    float* out = (float*)d_out;

    // ws layout (12,865,536 B total):
    // Wc 12,582,912 | bias 16,384 | hb0 131,072 | bar 4,096 | hb1 131,072
    // hfin (256 KB fp32) aliases Wc[0:262144) — Wc only read during the
    // one-time LDS stage, 511 barriers before any t=T-1 write. Safe.
    char* ws = (char*)d_ws;
    __bf16* Wc   = (__bf16*)ws;
    float*  bias = (float*)(ws + 12582912);
    __bf16* hb0  = (__bf16*)(ws + 12599296);
    GBar*   bar  = (GBar*)  (ws + 12730368);
    __bf16* hb1  = (__bf16*)(ws + 12734464);
    float*  hfin = (float*)ws;

    (void)hipMemsetAsync(ws + 12599296, 0, 131072 + 4096, stream);  // hb0 + bar
    convert_w<<<3072, 256, 0, stream>>>(Wx, Wh, Wc);
    make_bias<<<16, 256, 0, stream>>>(bx, bh, bias);

    lstm_persistent<<<NBLK, 256, 0, stream>>>(x, Wc, bias, hb0, hb1, hfin, bar);

    out_gemm<<<(B * O + 255) / 256, 256, 0, stream>>>(hfin, Why, bhy, out);
}

// Round 12
// 3502.511 us; speedup vs baseline: 2.9585x; 1.2795x over previous
//
#include <hip/hip_runtime.h>
#include <hip/hip_bf16.h>
#include <math.h>

// Problem constants: T=512, B=64, D=512, H=1024, O=512
constexpr int T = 512;
constexpr int B = 64;
constexpr int D = 512;
constexpr int H = 1024;
constexpr int O = 512;
constexpr int GROUPS = 2;          // independent batch groups (no cross-sync)
constexpr int BG   = B / GROUPS;   // 32 batch rows per group
constexpr int GBLK = 128;          // blocks per group (own the 4096 gate-cols)
constexpr int COLS = 32;           // gate-cols per block
constexpr int KCH  = (D + H) / 8;  // 192 k-chunks of 8 elems

typedef __attribute__((ext_vector_type(8))) __bf16 bf16x8;
typedef __attribute__((ext_vector_type(4))) float  floatx4;

// Per-group tree barrier (R11-verified): 8 sub counters (16 arrivals) -> root
// (8) -> fan-out flags. All relaxed; h visibility is physical (write-through
// stores, cache-bypass reads).
struct GBar {
    unsigned grp[8][32];     // arrival counters, one 128B line each
    unsigned root; unsigned p0[31];
    unsigned gflag[8][32];   // per-subgroup broadcast flags, one line each
};

// ---------------------------------------------------------------------------
// W' bf16, strip-major: Wc[strip(128)][kchunk(192)][nl(32)][8]; col reorder
// n = j*4+g. k<512 from Wx[g*H+j][k], else Wh[g*H+j][k-512]. Shared by both
// batch groups (read-only after conversion).
// ---------------------------------------------------------------------------
__global__ __launch_bounds__(256) void convert_w(
    const float* __restrict__ Wx, const float* __restrict__ Wh,
    __bf16* __restrict__ Wc)
{
    const int id = blockIdx.x * 256 + threadIdx.x;   // 128*192*32 = 786432
    if (id >= GBLK * KCH * COLS) return;
    const int nl     = id & 31;
    const int kchunk = (id >> 5) % KCH;
    const int strip  = id / (KCH * COLS);
    const int n = strip * COLS + nl;
    const int j = n >> 2, g = n & 3;
    const int k0 = kchunk * 8;
    const float* src = (k0 < D) ? &Wx[(size_t)(g * H + j) * D + k0]
                                : &Wh[(size_t)(g * H + j) * H + (k0 - D)];
    const float4 a = *(const float4*)src;
    const float4 b = *(const float4*)(src + 4);
    __bf16 t8[8] = {(__bf16)a.x,(__bf16)a.y,(__bf16)a.z,(__bf16)a.w,
                    (__bf16)b.x,(__bf16)b.y,(__bf16)b.z,(__bf16)b.w};
    *(uint4*)&Wc[(size_t)id * 8] = *(uint4*)t8;
}

__global__ __launch_bounds__(256) void make_bias(
    const float* __restrict__ bx, const float* __restrict__ bh,
    float* __restrict__ bias)
{
    const int n = blockIdx.x * 256 + threadIdx.x;
    if (n < 4 * H) {
        const int j = n >> 2, g = n & 3;
        bias[n] = bx[g * H + j] + bh[g * H + j];
    }
}

// ---------------------------------------------------------------------------
// Persistent LSTM, round 12: BATCH-SPLIT. The recurrence couples only the
// hidden dim; batch rows are independent. 2 groups x 128 blocks (all 256
// CUs), each group owns 32 batch rows + its own h ping/pong + its own R11
// barrier. Per block: 128 threads (2 waves = 2 m-tiles of 16 rows), same
// 32-col W strip in LDS, half the h bytes and MFMAs of R11. The two groups'
// serial chains (barrier hops, L3 RTTs) overlap in time.
// ---------------------------------------------------------------------------
__global__ __launch_bounds__(128, 1) void lstm_persistent(
    const float* __restrict__ x,     // [T,B,D] fp32
    const __bf16* __restrict__ Wc,   // strip-major bf16 (read once at start)
    const float* __restrict__ bias,  // [4096] reordered
    __bf16* __restrict__ hbufs,      // [GROUPS][2][BG*H] bf16 ping/pong
    float* __restrict__ hfin,        // [B,H] fp32 final h (aliases Wc head)
    GBar* bars)                      // [GROUPS]
{
    __shared__ __attribute__((aligned(16))) __bf16 wlds[KCH * COLS * 8]; // 96 KB
    __shared__ __attribute__((aligned(16))) float  G[32][COLS + 4];      // 4.6 KB

    const int tid   = threadIdx.x;
    const int wid   = tid >> 6;    // wave id == m-tile (16 batch rows), 0..1
    const int lane  = tid & 63;
    const int cm    = lane & 15;
    const int q     = lane >> 4;
    const int group = blockIdx.x >> 7;          // 0..1
    const int gb    = blockIdx.x & 127;         // block within group
    const int n0    = gb * COLS;
    GBar* bar = bars + group;
    __bf16* hb0 = hbufs + (size_t)group * 2 * BG * H;
    __bf16* hb1 = hb0 + BG * H;

    // ---- one-time: W strip -> LDS (6144 x 16B contiguous) ----
    {
        const uint4* wsrc = (const uint4*)(Wc + (size_t)gb * KCH * COLS * 8);
        uint4* wdst = (uint4*)wlds;
        for (int i = tid; i < KCH * COLS; i += 128) wdst[i] = wsrc[i];
    }
    // epilogue mapping: thread owns (local row eb, j=jbase,jbase+1)
    const int eb = tid >> 2;                    // 0..31 local batch row
    const int p  = tid & 3;
    const int jbase = (n0 >> 2) + p * 2;
    const float4 bias0 = *(const float4*)&bias[n0 + p * 8];
    const float4 bias1 = *(const float4*)&bias[n0 + p * 8 + 4];
    float c0 = 0.f, c1 = 0.f;
    __syncthreads();

    // global batch row for this lane's m-tile position
    const int grow = group * BG + wid * 16 + cm;
    const float* xrow = x + (size_t)grow * D + q * 8;
    const int    hoff = (wid * 16 + cm) * H + q * 8;   // within group h buffer
    const __bf16* wl  = wlds + (q * 32 + cm) * 8;

    floatx4 acc[2][2];   // [col-strip][k-parity]
    float4  xcur[16][2]; // prefetched x_t fragments

    auto loadx = [&](int tt) {
        const float* xr = xrow + (size_t)tt * (B * D);
        #pragma unroll
        for (int s = 0; s < 16; ++s) {
            xcur[s][0] = *(const float4*)(xr + s * 32);
            xcur[s][1] = *(const float4*)(xr + s * 32 + 4);
        }
    };
    auto xmfma = [&]() {
        acc[0][0] = (floatx4){0,0,0,0}; acc[0][1] = (floatx4){0,0,0,0};
        acc[1][0] = (floatx4){0,0,0,0}; acc[1][1] = (floatx4){0,0,0,0};
        #pragma unroll
        for (int s = 0; s < 16; ++s) {
            const float4 a0 = xcur[s][0], a1 = xcur[s][1];
            const bf16x8 af = {(__bf16)a0.x,(__bf16)a0.y,(__bf16)a0.z,(__bf16)a0.w,
                               (__bf16)a1.x,(__bf16)a1.y,(__bf16)a1.z,(__bf16)a1.w};
            const bf16x8 b0 = *(const bf16x8*)(wl + s * 1024);
            const bf16x8 b1 = *(const bf16x8*)(wl + s * 1024 + 128);
            acc[0][s & 1] = __builtin_amdgcn_mfma_f32_16x16x32_bf16(af, b0, acc[0][s & 1], 0, 0, 0);
            acc[1][s & 1] = __builtin_amdgcn_mfma_f32_16x16x32_bf16(af, b1, acc[1][s & 1], 0, 0, 0);
        }
    };

    loadx(0);
    xmfma();

    const int sub = gb >> 4;   // sub-group 0..7 within this group's barrier

    for (int t = 0; t < T; ++t) {
        const __bf16* hcur = (t & 1) ? hb1 : hb0;
        __bf16*       hnxt = (t & 1) ? hb0 : hb1;

        // ---- wait for step t-1's h (poll own sub-group flag line) ----
        if (t > 0) {
            if (tid == 0) {
                while (__hip_atomic_load(&bar->gflag[sub][0], __ATOMIC_RELAXED,
                                         __HIP_MEMORY_SCOPE_AGENT) < (unsigned)t)
                    __builtin_amdgcn_s_sleep(1);
            }
            __syncthreads();
        }

        // ---- h-part: K=512..1535. 32 coherent dwordx4 loads in ONE asm
        //      block + vmcnt(0); then 64 MFMAs from registers ----
        {
            const __bf16* hbase = hcur + hoff;   // per-lane, 16B aligned
            uint4 hv[32];
            asm volatile(
                "global_load_dwordx4 %0, %32, off sc0 sc1\n\t"
                "global_load_dwordx4 %1, %32, off offset:64 sc0 sc1\n\t"
                "global_load_dwordx4 %2, %32, off offset:128 sc0 sc1\n\t"
                "global_load_dwordx4 %3, %32, off offset:192 sc0 sc1\n\t"
                "global_load_dwordx4 %4, %32, off offset:256 sc0 sc1\n\t"
                "global_load_dwordx4 %5, %32, off offset:320 sc0 sc1\n\t"
                "global_load_dwordx4 %6, %32, off offset:384 sc0 sc1\n\t"
                "global_load_dwordx4 %7, %32, off offset:448 sc0 sc1\n\t"
                "global_load_dwordx4 %8, %32, off offset:512 sc0 sc1\n\t"
                "global_load_dwordx4 %9, %32, off offset:576 sc0 sc1\n\t"
                "global_load_dwordx4 %10, %32, off offset:640 sc0 sc1\n\t"
                "global_load_dwordx4 %11, %32, off offset:704 sc0 sc1\n\t"
                "global_load_dwordx4 %12, %32, off offset:768 sc0 sc1\n\t"
                "global_load_dwordx4 %13, %32, off offset:832 sc0 sc1\n\t"
                "global_load_dwordx4 %14, %32, off offset:896 sc0 sc1\n\t"
                "global_load_dwordx4 %15, %32, off offset:960 sc0 sc1\n\t"
                "global_load_dwordx4 %16, %32, off offset:1024 sc0 sc1\n\t"
                "global_load_dwordx4 %17, %32, off offset:1088 sc0 sc1\n\t"
                "global_load_dwordx4 %18, %32, off offset:1152 sc0 sc1\n\t"
                "global_load_dwordx4 %19, %32, off offset:1216 sc0 sc1\n\t"
                "global_load_dwordx4 %20, %32, off offset:1280 sc0 sc1\n\t"
                "global_load_dwordx4 %21, %32, off offset:1344 sc0 sc1\n\t"
                "global_load_dwordx4 %22, %32, off offset:1408 sc0 sc1\n\t"
                "global_load_dwordx4 %23, %32, off offset:1472 sc0 sc1\n\t"
                "global_load_dwordx4 %24, %32, off offset:1536 sc0 sc1\n\t"
                "global_load_dwordx4 %25, %32, off offset:1600 sc0 sc1\n\t"
                "global_load_dwordx4 %26, %32, off offset:1664 sc0 sc1\n\t"
                "global_load_dwordx4 %27, %32, off offset:1728 sc0 sc1\n\t"
                "global_load_dwordx4 %28, %32, off offset:1792 sc0 sc1\n\t"
                "global_load_dwordx4 %29, %32, off offset:1856 sc0 sc1\n\t"
                "global_load_dwordx4 %30, %32, off offset:1920 sc0 sc1\n\t"
                "global_load_dwordx4 %31, %32, off offset:1984 sc0 sc1\n\t"
                "s_waitcnt vmcnt(0)"
                : "=&v"(hv[0]),  "=&v"(hv[1]),  "=&v"(hv[2]),  "=&v"(hv[3]),
                  "=&v"(hv[4]),  "=&v"(hv[5]),  "=&v"(hv[6]),  "=&v"(hv[7]),
                  "=&v"(hv[8]),  "=&v"(hv[9]),  "=&v"(hv[10]), "=&v"(hv[11]),
                  "=&v"(hv[12]), "=&v"(hv[13]), "=&v"(hv[14]), "=&v"(hv[15]),
                  "=&v"(hv[16]), "=&v"(hv[17]), "=&v"(hv[18]), "=&v"(hv[19]),
                  "=&v"(hv[20]), "=&v"(hv[21]), "=&v"(hv[22]), "=&v"(hv[23]),
                  "=&v"(hv[24]), "=&v"(hv[25]), "=&v"(hv[26]), "=&v"(hv[27]),
                  "=&v"(hv[28]), "=&v"(hv[29]), "=&v"(hv[30]), "=&v"(hv[31])
                : "v"(hbase)
                : "memory");
            #pragma unroll
            for (int sg = 0; sg < 32; ++sg) {
                union { uint4 u; bf16x8 v; } hf; hf.u = hv[sg];
                const bf16x8 b0 = *(const bf16x8*)(wl + 16384 + sg * 1024);
                const bf16x8 b1 = *(const bf16x8*)(wl + 16384 + sg * 1024 + 128);
                acc[0][sg & 1] = __builtin_amdgcn_mfma_f32_16x16x32_bf16(hf.v, b0, acc[0][sg & 1], 0, 0, 0);
                acc[1][sg & 1] = __builtin_amdgcn_mfma_f32_16x16x32_bf16(hf.v, b1, acc[1][sg & 1], 0, 0, 0);
            }
        }
        const floatx4 av0 = acc[0][0] + acc[0][1];
        const floatx4 av1 = acc[1][0] + acc[1][1];

        // ---- transpose C via LDS ----
        #pragma unroll
        for (int r = 0; r < 4; ++r) {
            G[wid * 16 + q * 4 + r][cm]      = av0[r];
            G[wid * 16 + q * 4 + r][16 + cm] = av1[r];
        }

        // ---- prefetch x for t+1 (RTT hides under the epilogue) ----
        if (t + 1 < T) loadx(t + 1);

        __syncthreads();

        // ---- fused cell update: 2 (row,j) cells per thread ----
        const float4 g0 = *(const float4*)&G[eb][p * 8];
        const float4 g1 = *(const float4*)&G[eb][p * 8 + 4];
        const float i0 = 1.f / (1.f + expf(-(g0.x + bias0.x)));
        const float f0 = 1.f / (1.f + expf(-(g0.y + bias0.y)));
        const float o0 = 1.f / (1.f + expf(-(g0.z + bias0.z)));
        const float t0 = tanhf(g0.w + bias0.w);
        const float i1 = 1.f / (1.f + expf(-(g1.x + bias1.x)));
        const float f1 = 1.f / (1.f + expf(-(g1.y + bias1.y)));
        const float o1 = 1.f / (1.f + expf(-(g1.z + bias1.z)));
        const float t1 = tanhf(g1.w + bias1.w);
        c0 = f0 * c0 + i0 * t0;
        c1 = f1 * c1 + i1 * t1;
        const float hv0 = o0 * tanhf(c0);
        const float hv1 = o1 * tanhf(c1);
        const int hi = eb * H + jbase;
        union { __bf16 h2[2]; unsigned u; } hp;
        hp.h2[0] = (__bf16)hv0; hp.h2[1] = (__bf16)hv1;
        __hip_atomic_store((unsigned*)&hnxt[hi], hp.u, __ATOMIC_RELAXED,
                           __HIP_MEMORY_SCOPE_AGENT);   // write-through publish
        if (t == T - 1) {
            const int gr = group * BG + eb;
            hfin[gr * H + jbase] = hv0; hfin[gr * H + jbase + 1] = hv1;
        }

        __syncthreads();  // G reads done + h stores vmcnt-drained before arrive

        // ---- arrive (relaxed tree, fan-out flags), own group's barrier ----
        if (tid == 0) {
            const unsigned old = __hip_atomic_fetch_add(&bar->grp[sub][0], 1u,
                                    __ATOMIC_RELAXED, __HIP_MEMORY_SCOPE_AGENT);
            if (old == 16u * (unsigned)(t + 1) - 1u) {
                const unsigned r = __hip_atomic_fetch_add(&bar->root, 1u,
                                    __ATOMIC_RELAXED, __HIP_MEMORY_SCOPE_AGENT);
                if (r == 8u * (unsigned)(t + 1) - 1u) {
                    #pragma unroll
                    for (int k = 0; k < 8; ++k)
                        __hip_atomic_store(&bar->gflag[k][0], (unsigned)(t + 1),
                                           __ATOMIC_RELAXED, __HIP_MEMORY_SCOPE_AGENT);
                }
            }
        }
        // ---- x MFMAs for t+1 in the barrier-propagation shadow ----
        if (t + 1 < T) xmfma();
    }
}

// out[b,o] = h[b,:] . Why[o,:] + bhy[o]
__global__ __launch_bounds__(256) void out_gemm(
    const float* __restrict__ h, const float* __restrict__ Why,
    const float* __restrict__ bhy, float* __restrict__ out)
{
    const int idx = blockIdx.x * 256 + threadIdx.x;
    if (idx >= B * O) return;
    const int b = idx / O;
    const int o = idx % O;
    const float4* hv = (const float4*)&h[(size_t)b * H];
    const float4* wv = (const float4*)&Why[(size_t)o * H];
    float s = 0.f;
    #pragma unroll 4
    for (int k = 0; k < H / 4; ++k) {
        const float4 a = hv[k];
        const float4 w = wv[k];
        s += a.x * w.x + a.y * w.y + a.z * w.z + a.w * w.w;
    }
    out[idx] = s + bhy[o];
}

extern "C" void kernel_launch(void* const* d_in, const int* in_sizes, int n_in,
                              void* d_out, int out_size, void* d_ws, size_t ws_size,
                              hipStream_t stream) {
    const float* x   = (const float*)d_in[0];
    const float* Wx  = (const float*)d_in[1];
    const float* bx  = (const float*)d_in[2];
    const float* Wh  = (const float*)d_in[3];
    const float* bh  = (const float*)d_in[4];
    const float* Why = (const float*)d_in[5];
    const float* bhy = (const float*)d_in[6];
    float* out = (float*)d_out;

    // ws layout (12,869,632 B total):
    // Wc 12,582,912 | bias 16,384 @12,582,912 | hbufs 262,144 @12,599,296
    // bars 8,192 @12,861,440
    // hfin (256 KB fp32) aliases Wc[0:262144) — Wc only read during the
    // one-time LDS stage, 511 barriers before any t=T-1 write. Safe.
    char* ws = (char*)d_ws;
    __bf16* Wc    = (__bf16*)ws;
    float*  bias  = (float*)(ws + 12582912);
    __bf16* hbufs = (__bf16*)(ws + 12599296);   // [2][2][BG*H] = 256 KB
    GBar*   bars  = (GBar*)  (ws + 12861440);   // 2 x 4 KB
    float*  hfin  = (float*)ws;

    (void)hipMemsetAsync(ws + 12599296, 0, 262144 + 8192, stream);  // hbufs+bars
    convert_w<<<3072, 256, 0, stream>>>(Wx, Wh, Wc);
    make_bias<<<16, 256, 0, stream>>>(bx, bh, bias);

    lstm_persistent<<<GROUPS * GBLK, 128, 0, stream>>>(x, Wc, bias, hbufs,
                                                       hfin, bars);

    out_gemm<<<(B * O + 255) / 256, 256, 0, stream>>>(hfin, Why, bhy, out);
}

// Round 13
// 3472.876 us; speedup vs baseline: 2.9838x; 1.0085x over previous
//
#include <hip/hip_runtime.h>
#include <hip/hip_bf16.h>
#include <math.h>

// Problem constants: T=512, B=64, D=512, H=1024, O=512
constexpr int T = 512;
constexpr int B = 64;
constexpr int D = 512;
constexpr int H = 1024;
constexpr int O = 512;
constexpr int GROUPS = 2;          // independent batch groups (no cross-sync)
constexpr int BG   = B / GROUPS;   // 32 batch rows per group
constexpr int GBLK = 128;          // blocks per group (own the 4096 gate-cols)
constexpr int COLS = 32;           // gate-cols per block
constexpr int KCH  = (D + H) / 8;  // 192 k-chunks of 8 elems

typedef __attribute__((ext_vector_type(8))) __bf16 bf16x8;
typedef __attribute__((ext_vector_type(4))) float  floatx4;

// Store-based barrier (round 13): each block's leader STORES (t+1) to its own
// 128B line (no atomic serialization — lock-stepped arrivals hit distinct
// lines). Root block's wave 0 polls all 128 lines in parallel (2 per lane,
// ballot), then 8 lanes fan out per-sub flags. All relaxed sc0sc1 ops;
// h visibility is physical (write-through stores, cache-bypass reads).
struct GBar {
    unsigned arr[GBLK][32];  // arrival lines, 128B each (16 KB)
    unsigned gflag[8][32];   // per-subgroup broadcast flags (1 KB)
};

// ---------------------------------------------------------------------------
// W' bf16, strip-major: Wc[strip(128)][kchunk(192)][nl(32)][8]; col reorder
// n = j*4+g. k<512 from Wx[g*H+j][k], else Wh[g*H+j][k-512]. Shared by both
// batch groups (read-only after conversion).
// ---------------------------------------------------------------------------
__global__ __launch_bounds__(256) void convert_w(
    const float* __restrict__ Wx, const float* __restrict__ Wh,
    __bf16* __restrict__ Wc)
{
    const int id = blockIdx.x * 256 + threadIdx.x;   // 128*192*32 = 786432
    if (id >= GBLK * KCH * COLS) return;
    const int nl     = id & 31;
    const int kchunk = (id >> 5) % KCH;
    const int strip  = id / (KCH * COLS);
    const int n = strip * COLS + nl;
    const int j = n >> 2, g = n & 3;
    const int k0 = kchunk * 8;
    const float* src = (k0 < D) ? &Wx[(size_t)(g * H + j) * D + k0]
                                : &Wh[(size_t)(g * H + j) * H + (k0 - D)];
    const float4 a = *(const float4*)src;
    const float4 b = *(const float4*)(src + 4);
    __bf16 t8[8] = {(__bf16)a.x,(__bf16)a.y,(__bf16)a.z,(__bf16)a.w,
                    (__bf16)b.x,(__bf16)b.y,(__bf16)b.z,(__bf16)b.w};
    *(uint4*)&Wc[(size_t)id * 8] = *(uint4*)t8;
}

__global__ __launch_bounds__(256) void make_bias(
    const float* __restrict__ bx, const float* __restrict__ bh,
    float* __restrict__ bias)
{
    const int n = blockIdx.x * 256 + threadIdx.x;
    if (n < 4 * H) {
        const int j = n >> 2, g = n & 3;
        bias[n] = bx[g * H + j] + bh[g * H + j];
    }
}

// ---------------------------------------------------------------------------
// Persistent LSTM, round 13 = round-12 batch-split core + three shavings:
//  (1) store-based barrier with wave-parallel root detection (no atomic
//      serialization on lock-stepped arrivals),
//  (2) in-register 4x4 quad transpose (__shfl_xor butterfly) replaces the
//      G-LDS round-trip epilogue: 3 syncs/step -> 1,
//  (3) all-lane flag polling (coalesced same-address load, no wait sync).
// ---------------------------------------------------------------------------
__global__ __launch_bounds__(128, 1) void lstm_persistent(
    const float* __restrict__ x,     // [T,B,D] fp32
    const __bf16* __restrict__ Wc,   // strip-major bf16 (read once at start)
    const float* __restrict__ bias,  // [4096] reordered
    __bf16* __restrict__ hbufs,      // [GROUPS][2][BG*H] bf16 ping/pong
    float* __restrict__ hfin,        // [B,H] fp32 final h (aliases Wc head)
    GBar* bars)                      // [GROUPS]
{
    __shared__ __attribute__((aligned(16))) __bf16 wlds[KCH * COLS * 8]; // 96 KB

    const int tid   = threadIdx.x;
    const int wid   = tid >> 6;    // wave id == m-tile (16 batch rows), 0..1
    const int lane  = tid & 63;
    const int cm    = lane & 15;
    const int q     = lane >> 4;
    const int group = blockIdx.x >> 7;          // 0..1
    const int gb    = blockIdx.x & 127;         // block within group
    const int n0    = gb * COLS;
    GBar* bar = bars + group;
    __bf16* hb0 = hbufs + (size_t)group * 2 * BG * H;
    __bf16* hb1 = hb0 + BG * H;

    // ---- one-time: W strip -> LDS (6144 x 16B contiguous) ----
    {
        const uint4* wsrc = (const uint4*)(Wc + (size_t)gb * KCH * COLS * 8);
        uint4* wdst = (uint4*)wlds;
        for (int i = tid; i < KCH * COLS; i += 128) wdst[i] = wsrc[i];
    }
    // post-transpose epilogue mapping: lane owns row_l = wid*16+q*4+(cm&3),
    // j0 = gb*8 + (cm>>2) (strip 0), j1 = j0 + 4 (strip 1). c in registers.
    const int p4 = cm & 3;
    const int jl = cm >> 2;
    const int row_l = wid * 16 + q * 4 + p4;     // 0..31 local batch row
    const float4 bias0q = *(const float4*)&bias[n0 + jl * 4];        // strip 0
    const float4 bias1q = *(const float4*)&bias[n0 + 16 + jl * 4];   // strip 1
    float c0 = 0.f, c1 = 0.f;
    __syncthreads();

    // global batch row for this lane's A-fragment position
    const int grow = group * BG + wid * 16 + cm;
    const float* xrow = x + (size_t)grow * D + q * 8;
    const int    hoff = (wid * 16 + cm) * H + q * 8;   // within group h buffer
    const __bf16* wl  = wlds + (q * 32 + cm) * 8;

    floatx4 acc[2][2];   // [col-strip][k-parity]
    float4  xcur[16][2]; // prefetched x_t fragments

    auto loadx = [&](int tt) {
        const float* xr = xrow + (size_t)tt * (B * D);
        #pragma unroll
        for (int s = 0; s < 16; ++s) {
            xcur[s][0] = *(const float4*)(xr + s * 32);
            xcur[s][1] = *(const float4*)(xr + s * 32 + 4);
        }
    };
    auto xmfma = [&]() {
        acc[0][0] = (floatx4){0,0,0,0}; acc[0][1] = (floatx4){0,0,0,0};
        acc[1][0] = (floatx4){0,0,0,0}; acc[1][1] = (floatx4){0,0,0,0};
        #pragma unroll
        for (int s = 0; s < 16; ++s) {
            const float4 a0 = xcur[s][0], a1 = xcur[s][1];
            const bf16x8 af = {(__bf16)a0.x,(__bf16)a0.y,(__bf16)a0.z,(__bf16)a0.w,
                               (__bf16)a1.x,(__bf16)a1.y,(__bf16)a1.z,(__bf16)a1.w};
            const bf16x8 b0 = *(const bf16x8*)(wl + s * 1024);
            const bf16x8 b1 = *(const bf16x8*)(wl + s * 1024 + 128);
            acc[0][s & 1] = __builtin_amdgcn_mfma_f32_16x16x32_bf16(af, b0, acc[0][s & 1], 0, 0, 0);
            acc[1][s & 1] = __builtin_amdgcn_mfma_f32_16x16x32_bf16(af, b1, acc[1][s & 1], 0, 0, 0);
        }
    };

    // 4x4 transpose across lane-quads: in V[r] = C[row q*4+r][gate p4],
    // out V[r] = C[row q*4+p4][gate r].   (verified butterfly)
    auto quadT = [&](float v[4]) {
        float w0 = __shfl_xor(v[1], 1), w1 = __shfl_xor(v[0], 1);
        float w2 = __shfl_xor(v[3], 1), w3 = __shfl_xor(v[2], 1);
        if (p4 & 1) { v[0] = w0; v[2] = w2; } else { v[1] = w1; v[3] = w3; }
        w0 = __shfl_xor(v[2], 2); w1 = __shfl_xor(v[3], 2);
        w2 = __shfl_xor(v[0], 2); w3 = __shfl_xor(v[1], 2);
        if (p4 & 2) { v[0] = w0; v[1] = w1; } else { v[2] = w2; v[3] = w3; }
    };

    loadx(0);
    xmfma();

    const int sub = gb >> 4;   // sub-group 0..7 (flag fan-out granularity)

    for (int t = 0; t < T; ++t) {
        const __bf16* hcur = (t & 1) ? hb1 : hb0;
        __bf16*       hnxt = (t & 1) ? hb0 : hb1;

        // ---- wait for step t-1's h: ALL lanes poll own sub flag ----
        if (t > 0) {
            while (__hip_atomic_load(&bar->gflag[sub][0], __ATOMIC_RELAXED,
                                     __HIP_MEMORY_SCOPE_AGENT) < (unsigned)t)
                __builtin_amdgcn_s_sleep(1);
        }

        // ---- h-part: K=512..1535. 32 coherent dwordx4 loads in ONE asm
        //      block + vmcnt(0); then 64 MFMAs from registers ----
        {
            const __bf16* hbase = hcur + hoff;   // per-lane, 16B aligned
            uint4 hv[32];
            asm volatile(
                "global_load_dwordx4 %0, %32, off sc0 sc1\n\t"
                "global_load_dwordx4 %1, %32, off offset:64 sc0 sc1\n\t"
                "global_load_dwordx4 %2, %32, off offset:128 sc0 sc1\n\t"
                "global_load_dwordx4 %3, %32, off offset:192 sc0 sc1\n\t"
                "global_load_dwordx4 %4, %32, off offset:256 sc0 sc1\n\t"
                "global_load_dwordx4 %5, %32, off offset:320 sc0 sc1\n\t"
                "global_load_dwordx4 %6, %32, off offset:384 sc0 sc1\n\t"
                "global_load_dwordx4 %7, %32, off offset:448 sc0 sc1\n\t"
                "global_load_dwordx4 %8, %32, off offset:512 sc0 sc1\n\t"
                "global_load_dwordx4 %9, %32, off offset:576 sc0 sc1\n\t"
                "global_load_dwordx4 %10, %32, off offset:640 sc0 sc1\n\t"
                "global_load_dwordx4 %11, %32, off offset:704 sc0 sc1\n\t"
                "global_load_dwordx4 %12, %32, off offset:768 sc0 sc1\n\t"
                "global_load_dwordx4 %13, %32, off offset:832 sc0 sc1\n\t"
                "global_load_dwordx4 %14, %32, off offset:896 sc0 sc1\n\t"
                "global_load_dwordx4 %15, %32, off offset:960 sc0 sc1\n\t"
                "global_load_dwordx4 %16, %32, off offset:1024 sc0 sc1\n\t"
                "global_load_dwordx4 %17, %32, off offset:1088 sc0 sc1\n\t"
                "global_load_dwordx4 %18, %32, off offset:1152 sc0 sc1\n\t"
                "global_load_dwordx4 %19, %32, off offset:1216 sc0 sc1\n\t"
                "global_load_dwordx4 %20, %32, off offset:1280 sc0 sc1\n\t"
                "global_load_dwordx4 %21, %32, off offset:1344 sc0 sc1\n\t"
                "global_load_dwordx4 %22, %32, off offset:1408 sc0 sc1\n\t"
                "global_load_dwordx4 %23, %32, off offset:1472 sc0 sc1\n\t"
                "global_load_dwordx4 %24, %32, off offset:1536 sc0 sc1\n\t"
                "global_load_dwordx4 %25, %32, off offset:1600 sc0 sc1\n\t"
                "global_load_dwordx4 %26, %32, off offset:1664 sc0 sc1\n\t"
                "global_load_dwordx4 %27, %32, off offset:1728 sc0 sc1\n\t"
                "global_load_dwordx4 %28, %32, off offset:1792 sc0 sc1\n\t"
                "global_load_dwordx4 %29, %32, off offset:1856 sc0 sc1\n\t"
                "global_load_dwordx4 %30, %32, off offset:1920 sc0 sc1\n\t"
                "global_load_dwordx4 %31, %32, off offset:1984 sc0 sc1\n\t"
                "s_waitcnt vmcnt(0)"
                : "=&v"(hv[0]),  "=&v"(hv[1]),  "=&v"(hv[2]),  "=&v"(hv[3]),
                  "=&v"(hv[4]),  "=&v"(hv[5]),  "=&v"(hv[6]),  "=&v"(hv[7]),
                  "=&v"(hv[8]),  "=&v"(hv[9]),  "=&v"(hv[10]), "=&v"(hv[11]),
                  "=&v"(hv[12]), "=&v"(hv[13]), "=&v"(hv[14]), "=&v"(hv[15]),
                  "=&v"(hv[16]), "=&v"(hv[17]), "=&v"(hv[18]), "=&v"(hv[19]),
                  "=&v"(hv[20]), "=&v"(hv[21]), "=&v"(hv[22]), "=&v"(hv[23]),
                  "=&v"(hv[24]), "=&v"(hv[25]), "=&v"(hv[26]), "=&v"(hv[27]),
                  "=&v"(hv[28]), "=&v"(hv[29]), "=&v"(hv[30]), "=&v"(hv[31])
                : "v"(hbase)
                : "memory");
            #pragma unroll
            for (int sg = 0; sg < 32; ++sg) {
                union { uint4 u; bf16x8 v; } hf; hf.u = hv[sg];
                const bf16x8 b0 = *(const bf16x8*)(wl + 16384 + sg * 1024);
                const bf16x8 b1 = *(const bf16x8*)(wl + 16384 + sg * 1024 + 128);
                acc[0][sg & 1] = __builtin_amdgcn_mfma_f32_16x16x32_bf16(hf.v, b0, acc[0][sg & 1], 0, 0, 0);
                acc[1][sg & 1] = __builtin_amdgcn_mfma_f32_16x16x32_bf16(hf.v, b1, acc[1][sg & 1], 0, 0, 0);
            }
        }
        const floatx4 av0 = acc[0][0] + acc[0][1];
        const floatx4 av1 = acc[1][0] + acc[1][1];

        // ---- in-register quad transpose (replaces LDS round-trip) ----
        float g0v[4] = {av0.x, av0.y, av0.z, av0.w};
        float g1v[4] = {av1.x, av1.y, av1.z, av1.w};
        quadT(g0v);
        quadT(g1v);

        // ---- prefetch x for t+1 (RTT hides under the cell update) ----
        if (t + 1 < T) loadx(t + 1);

        // ---- fused cell update: lane owns (row_l, j0) and (row_l, j1) ----
        const float i0 = 1.f / (1.f + expf(-(g0v[0] + bias0q.x)));
        const float f0 = 1.f / (1.f + expf(-(g0v[1] + bias0q.y)));
        const float o0 = 1.f / (1.f + expf(-(g0v[2] + bias0q.z)));
        const float t0 = tanhf(g0v[3] + bias0q.w);
        const float i1 = 1.f / (1.f + expf(-(g1v[0] + bias1q.x)));
        const float f1 = 1.f / (1.f + expf(-(g1v[1] + bias1q.y)));
        const float o1 = 1.f / (1.f + expf(-(g1v[2] + bias1q.z)));
        const float t1 = tanhf(g1v[3] + bias1q.w);
        c0 = f0 * c0 + i0 * t0;
        c1 = f1 * c1 + i1 * t1;
        const float hv0 = o0 * tanhf(c0);
        const float hv1 = o1 * tanhf(c1);
        const int j0 = gb * 8 + jl;          // strip-0 hidden index
        const int hi = row_l * H + j0;
        union { __bf16 b; unsigned short u; } s0, s1;
        s0.b = (__bf16)hv0; s1.b = (__bf16)hv1;
        __hip_atomic_store((unsigned short*)&hnxt[hi], s0.u, __ATOMIC_RELAXED,
                           __HIP_MEMORY_SCOPE_AGENT);
        __hip_atomic_store((unsigned short*)&hnxt[hi + 4], s1.u, __ATOMIC_RELAXED,
                           __HIP_MEMORY_SCOPE_AGENT);
        if (t == T - 1) {
            const int gr = group * BG + row_l;
            hfin[gr * H + j0]     = hv0;
            hfin[gr * H + j0 + 4] = hv1;
        }

        __syncthreads();  // drain all threads' h stores (vmcnt0) before arrive

        // ---- arrive: leader STORES to its own line (no serialization) ----
        if (tid == 0)
            __hip_atomic_store(&bar->arr[gb][0], (unsigned)(t + 1),
                               __ATOMIC_RELAXED, __HIP_MEMORY_SCOPE_AGENT);

        // ---- x MFMAs for t+1 in the detection/propagation shadow ----
        if (t + 1 < T) xmfma();

        // ---- root block: wave-parallel detect + fan-out ----
        if (gb == 0 && tid < 64) {
            const unsigned want = (unsigned)(t + 1);
            for (;;) {
                const unsigned a = __hip_atomic_load(&bar->arr[2 * tid][0],
                                        __ATOMIC_RELAXED, __HIP_MEMORY_SCOPE_AGENT);
                const unsigned b = __hip_atomic_load(&bar->arr[2 * tid + 1][0],
                                        __ATOMIC_RELAXED, __HIP_MEMORY_SCOPE_AGENT);
                if (__ballot((a >= want) && (b >= want)) == ~0ull) break;
            }
            if (tid < 8)
                __hip_atomic_store(&bar->gflag[tid][0], want,
                                   __ATOMIC_RELAXED, __HIP_MEMORY_SCOPE_AGENT);
        }
    }
}

// out[b,o] = h[b,:] . Why[o,:] + bhy[o]
__global__ __launch_bounds__(256) void out_gemm(
    const float* __restrict__ h, const float* __restrict__ Why,
    const float* __restrict__ bhy, float* __restrict__ out)
{
    const int idx = blockIdx.x * 256 + threadIdx.x;
    if (idx >= B * O) return;
    const int b = idx / O;
    const int o = idx % O;
    const float4* hv = (const float4*)&h[(size_t)b * H];
    const float4* wv = (const float4*)&Why[(size_t)o * H];
    float s = 0.f;
    #pragma unroll 4
    for (int k = 0; k < H / 4; ++k) {
        const float4 a = hv[k];
        const float4 w = wv[k];
        s += a.x * w.x + a.y * w.y + a.z * w.z + a.w * w.w;
    }
    out[idx] = s + bhy[o];
}

extern "C" void kernel_launch(void* const* d_in, const int* in_sizes, int n_in,
                              void* d_out, int out_size, void* d_ws, size_t ws_size,
                              hipStream_t stream) {
    const float* x   = (const float*)d_in[0];
    const float* Wx  = (const float*)d_in[1];
    const float* bx  = (const float*)d_in[2];
    const float* Wh  = (const float*)d_in[3];
    const float* bh  = (const float*)d_in[4];
    const float* Why = (const float*)d_in[5];
    const float* bhy = (const float*)d_in[6];
    float* out = (float*)d_out;

    // ws layout (~12.90 MB total):
    // Wc 12,582,912 | bias 16,384 @12,582,912 | hbufs 262,144 @12,599,296
    // bars 2 x 17,408 @12,861,440
    // hfin (256 KB fp32) aliases Wc[0:262144) — Wc only read during the
    // one-time LDS stage, 511 barriers before any t=T-1 write. Safe.
    char* ws = (char*)d_ws;
    __bf16* Wc    = (__bf16*)ws;
    float*  bias  = (float*)(ws + 12582912);
    __bf16* hbufs = (__bf16*)(ws + 12599296);   // [2][2][BG*H] = 256 KB
    GBar*   bars  = (GBar*)  (ws + 12861440);   // 2 x 17,408 B
    float*  hfin  = (float*)ws;

    (void)hipMemsetAsync(ws + 12599296, 0, 262144 + 2 * sizeof(GBar), stream);
    convert_w<<<3072, 256, 0, stream>>>(Wx, Wh, Wc);
    make_bias<<<16, 256, 0, stream>>>(bx, bh, bias);

    lstm_persistent<<<GROUPS * GBLK, 128, 0, stream>>>(x, Wc, bias, hbufs,
                                                       hfin, bars);

    out_gemm<<<(B * O + 255) / 256, 256, 0, stream>>>(hfin, Why, bhy, out);
}

// Round 14
// 3255.096 us; speedup vs baseline: 3.1834x; 1.0669x over previous
//
#include <hip/hip_runtime.h>
#include <hip/hip_bf16.h>
#include <math.h>

// Problem constants: T=512, B=64, D=512, H=1024, O=512
constexpr int T = 512;
constexpr int B = 64;
constexpr int D = 512;
constexpr int H = 1024;
constexpr int O = 512;
constexpr int GROUPS = 2;          // independent batch groups (no cross-sync)
constexpr int BG   = B / GROUPS;   // 32 batch rows per group
constexpr int GBLK = 128;          // blocks per group (own the 4096 gate-cols)
constexpr int COLS = 32;           // gate-cols per block
constexpr int KCH  = (D + H) / 8;  // 192 k-chunks of 8 elems

typedef __attribute__((ext_vector_type(8))) __bf16 bf16x8;
typedef __attribute__((ext_vector_type(4))) float  floatx4;

// Round-14 barrier: arrival lines ONLY. Each block's wave-0 directly polls all
// 128 lines (2/lane + ballot) — no root, no fanout, no flag-observe hop.
struct GBar {
    unsigned arr[GBLK][32];  // one 128B line per block (16 KB)
};

// ---------------------------------------------------------------------------
// W' bf16, strip-major: Wc[strip(128)][kchunk(192)][nl(32)][8].
// Column reorder (round 14, even/odd interleave): within block gb,
//   nl -> s=nl>>4 (strip), jl=(nl>>2)&3, g=nl&3 ; j = gb*8 + 2*jl + s.
// Strip0 = even local j, strip1 = odd local j -> epilogue lane owns the
// ADJACENT pair (j, j+1) -> single 4B h-store.
// k<512 from Wx[g*H+j][k], else Wh[g*H+j][k-512].
// ---------------------------------------------------------------------------
__global__ __launch_bounds__(256) void convert_w(
    const float* __restrict__ Wx, const float* __restrict__ Wh,
    __bf16* __restrict__ Wc)
{
    const int id = blockIdx.x * 256 + threadIdx.x;   // 128*192*32 = 786432
    if (id >= GBLK * KCH * COLS) return;
    const int nl     = id & 31;
    const int kchunk = (id >> 5) % KCH;
    const int strip  = id / (KCH * COLS);
    const int s  = nl >> 4;
    const int jl = (nl >> 2) & 3;
    const int g  = nl & 3;
    const int j  = strip * 8 + 2 * jl + s;
    const int k0 = kchunk * 8;
    const float* src = (k0 < D) ? &Wx[(size_t)(g * H + j) * D + k0]
                                : &Wh[(size_t)(g * H + j) * H + (k0 - D)];
    const float4 a = *(const float4*)src;
    const float4 b = *(const float4*)(src + 4);
    __bf16 t8[8] = {(__bf16)a.x,(__bf16)a.y,(__bf16)a.z,(__bf16)a.w,
                    (__bf16)b.x,(__bf16)b.y,(__bf16)b.z,(__bf16)b.w};
    *(uint4*)&Wc[(size_t)id * 8] = *(uint4*)t8;
}

__global__ __launch_bounds__(256) void make_bias(
    const float* __restrict__ bx, const float* __restrict__ bh,
    float* __restrict__ bias)
{
    const int n = blockIdx.x * 256 + threadIdx.x;
    if (n < 4 * H) {
        const int gbn = n >> 5, nl = n & 31;
        const int s  = nl >> 4;
        const int jl = (nl >> 2) & 3;
        const int g  = nl & 3;
        const int j  = gbn * 8 + 2 * jl + s;
        bias[n] = bx[g * H + j] + bh[g * H + j];
    }
}

// ---------------------------------------------------------------------------
// Persistent LSTM, round 14 = round-13 core with:
//  (1) DIRECT arrival detection: each block's wave-0 polls all 128 arrival
//      lines (2/lane, ballot) — collapses arrive->root->fanout->observe
//      (3 L3 hops) to arrive->observe (1 hop).
//  (2) even/odd j interleave -> lane's two outputs adjacent -> one 4B
//      h-store (restores R12 write packing; halves WRITE_SIZE + drain).
// ---------------------------------------------------------------------------
__global__ __launch_bounds__(128, 1) void lstm_persistent(
    const float* __restrict__ x,     // [T,B,D] fp32
    const __bf16* __restrict__ Wc,   // strip-major bf16 (read once at start)
    const float* __restrict__ bias,  // [4096] reordered
    __bf16* __restrict__ hbufs,      // [GROUPS][2][BG*H] bf16 ping/pong
    float* __restrict__ hfin,        // [B,H] fp32 final h (aliases Wc head)
    GBar* bars)                      // [GROUPS]
{
    __shared__ __attribute__((aligned(16))) __bf16 wlds[KCH * COLS * 8]; // 96 KB

    const int tid   = threadIdx.x;
    const int wid   = tid >> 6;    // wave id == m-tile (16 batch rows), 0..1
    const int lane  = tid & 63;
    const int cm    = lane & 15;
    const int q     = lane >> 4;
    const int group = blockIdx.x >> 7;          // 0..1
    const int gb    = blockIdx.x & 127;         // block within group
    const int n0    = gb * COLS;
    GBar* bar = bars + group;
    __bf16* hb0 = hbufs + (size_t)group * 2 * BG * H;
    __bf16* hb1 = hb0 + BG * H;

    // ---- one-time: W strip -> LDS (6144 x 16B contiguous) ----
    {
        const uint4* wsrc = (const uint4*)(Wc + (size_t)gb * KCH * COLS * 8);
        uint4* wdst = (uint4*)wlds;
        for (int i = tid; i < KCH * COLS; i += 128) wdst[i] = wsrc[i];
    }
    // epilogue mapping: lane owns row_l = wid*16+q*4+(cm&3) and the ADJACENT
    // hidden pair j0 = gb*8 + 2*(cm>>2) (strip0=even), j0+1 (strip1=odd).
    const int p4 = cm & 3;
    const int jl = cm >> 2;
    const int row_l = wid * 16 + q * 4 + p4;     // 0..31 local batch row
    const float4 bias0q = *(const float4*)&bias[n0 + jl * 4];        // strip 0
    const float4 bias1q = *(const float4*)&bias[n0 + 16 + jl * 4];   // strip 1
    float c0 = 0.f, c1 = 0.f;
    __syncthreads();

    // global batch row for this lane's A-fragment position
    const int grow = group * BG + wid * 16 + cm;
    const float* xrow = x + (size_t)grow * D + q * 8;
    const int    hoff = (wid * 16 + cm) * H + q * 8;   // within group h buffer
    const __bf16* wl  = wlds + (q * 32 + cm) * 8;

    floatx4 acc[2][2];   // [col-strip][k-parity]
    float4  xcur[16][2]; // prefetched x_t fragments

    auto loadx = [&](int tt) {
        const float* xr = xrow + (size_t)tt * (B * D);
        #pragma unroll
        for (int s = 0; s < 16; ++s) {
            xcur[s][0] = *(const float4*)(xr + s * 32);
            xcur[s][1] = *(const float4*)(xr + s * 32 + 4);
        }
    };
    auto xmfma = [&]() {
        acc[0][0] = (floatx4){0,0,0,0}; acc[0][1] = (floatx4){0,0,0,0};
        acc[1][0] = (floatx4){0,0,0,0}; acc[1][1] = (floatx4){0,0,0,0};
        #pragma unroll
        for (int s = 0; s < 16; ++s) {
            const float4 a0 = xcur[s][0], a1 = xcur[s][1];
            const bf16x8 af = {(__bf16)a0.x,(__bf16)a0.y,(__bf16)a0.z,(__bf16)a0.w,
                               (__bf16)a1.x,(__bf16)a1.y,(__bf16)a1.z,(__bf16)a1.w};
            const bf16x8 b0 = *(const bf16x8*)(wl + s * 1024);
            const bf16x8 b1 = *(const bf16x8*)(wl + s * 1024 + 128);
            acc[0][s & 1] = __builtin_amdgcn_mfma_f32_16x16x32_bf16(af, b0, acc[0][s & 1], 0, 0, 0);
            acc[1][s & 1] = __builtin_amdgcn_mfma_f32_16x16x32_bf16(af, b1, acc[1][s & 1], 0, 0, 0);
        }
    };

    // 4x4 transpose across lane-quads: in V[r] = C[row q*4+r][gate p4],
    // out V[r] = C[row q*4+p4][gate r].   (R13-verified butterfly)
    auto quadT = [&](float v[4]) {
        float w0 = __shfl_xor(v[1], 1), w1 = __shfl_xor(v[0], 1);
        float w2 = __shfl_xor(v[3], 1), w3 = __shfl_xor(v[2], 1);
        if (p4 & 1) { v[0] = w0; v[2] = w2; } else { v[1] = w1; v[3] = w3; }
        w0 = __shfl_xor(v[2], 2); w1 = __shfl_xor(v[3], 2);
        w2 = __shfl_xor(v[0], 2); w3 = __shfl_xor(v[1], 2);
        if (p4 & 2) { v[0] = w0; v[1] = w1; } else { v[2] = w2; v[3] = w3; }
    };

    loadx(0);
    xmfma();

    for (int t = 0; t < T; ++t) {
        const __bf16* hcur = (t & 1) ? hb1 : hb0;
        __bf16*       hnxt = (t & 1) ? hb0 : hb1;

        // ---- wait: wave-0 directly polls all 128 arrival lines ----
        if (t > 0) {
            if (wid == 0) {
                const unsigned want = (unsigned)t;
                for (;;) {
                    const unsigned a = __hip_atomic_load(&bar->arr[2 * lane][0],
                                            __ATOMIC_RELAXED, __HIP_MEMORY_SCOPE_AGENT);
                    const unsigned b = __hip_atomic_load(&bar->arr[2 * lane + 1][0],
                                            __ATOMIC_RELAXED, __HIP_MEMORY_SCOPE_AGENT);
                    if (__ballot((a >= want) && (b >= want)) == ~0ull) break;
                    __builtin_amdgcn_s_sleep(1);
                }
            }
            __syncthreads();
        }

        // ---- h-part: K=512..1535. 32 coherent dwordx4 loads in ONE asm
        //      block + vmcnt(0); then 64 MFMAs from registers ----
        {
            const __bf16* hbase = hcur + hoff;   // per-lane, 16B aligned
            uint4 hv[32];
            asm volatile(
                "global_load_dwordx4 %0, %32, off sc0 sc1\n\t"
                "global_load_dwordx4 %1, %32, off offset:64 sc0 sc1\n\t"
                "global_load_dwordx4 %2, %32, off offset:128 sc0 sc1\n\t"
                "global_load_dwordx4 %3, %32, off offset:192 sc0 sc1\n\t"
                "global_load_dwordx4 %4, %32, off offset:256 sc0 sc1\n\t"
                "global_load_dwordx4 %5, %32, off offset:320 sc0 sc1\n\t"
                "global_load_dwordx4 %6, %32, off offset:384 sc0 sc1\n\t"
                "global_load_dwordx4 %7, %32, off offset:448 sc0 sc1\n\t"
                "global_load_dwordx4 %8, %32, off offset:512 sc0 sc1\n\t"
                "global_load_dwordx4 %9, %32, off offset:576 sc0 sc1\n\t"
                "global_load_dwordx4 %10, %32, off offset:640 sc0 sc1\n\t"
                "global_load_dwordx4 %11, %32, off offset:704 sc0 sc1\n\t"
                "global_load_dwordx4 %12, %32, off offset:768 sc0 sc1\n\t"
                "global_load_dwordx4 %13, %32, off offset:832 sc0 sc1\n\t"
                "global_load_dwordx4 %14, %32, off offset:896 sc0 sc1\n\t"
                "global_load_dwordx4 %15, %32, off offset:960 sc0 sc1\n\t"
                "global_load_dwordx4 %16, %32, off offset:1024 sc0 sc1\n\t"
                "global_load_dwordx4 %17, %32, off offset:1088 sc0 sc1\n\t"
                "global_load_dwordx4 %18, %32, off offset:1152 sc0 sc1\n\t"
                "global_load_dwordx4 %19, %32, off offset:1216 sc0 sc1\n\t"
                "global_load_dwordx4 %20, %32, off offset:1280 sc0 sc1\n\t"
                "global_load_dwordx4 %21, %32, off offset:1344 sc0 sc1\n\t"
                "global_load_dwordx4 %22, %32, off offset:1408 sc0 sc1\n\t"
                "global_load_dwordx4 %23, %32, off offset:1472 sc0 sc1\n\t"
                "global_load_dwordx4 %24, %32, off offset:1536 sc0 sc1\n\t"
                "global_load_dwordx4 %25, %32, off offset:1600 sc0 sc1\n\t"
                "global_load_dwordx4 %26, %32, off offset:1664 sc0 sc1\n\t"
                "global_load_dwordx4 %27, %32, off offset:1728 sc0 sc1\n\t"
                "global_load_dwordx4 %28, %32, off offset:1792 sc0 sc1\n\t"
                "global_load_dwordx4 %29, %32, off offset:1856 sc0 sc1\n\t"
                "global_load_dwordx4 %30, %32, off offset:1920 sc0 sc1\n\t"
                "global_load_dwordx4 %31, %32, off offset:1984 sc0 sc1\n\t"
                "s_waitcnt vmcnt(0)"
                : "=&v"(hv[0]),  "=&v"(hv[1]),  "=&v"(hv[2]),  "=&v"(hv[3]),
                  "=&v"(hv[4]),  "=&v"(hv[5]),  "=&v"(hv[6]),  "=&v"(hv[7]),
                  "=&v"(hv[8]),  "=&v"(hv[9]),  "=&v"(hv[10]), "=&v"(hv[11]),
                  "=&v"(hv[12]), "=&v"(hv[13]), "=&v"(hv[14]), "=&v"(hv[15]),
                  "=&v"(hv[16]), "=&v"(hv[17]), "=&v"(hv[18]), "=&v"(hv[19]),
                  "=&v"(hv[20]), "=&v"(hv[21]), "=&v"(hv[22]), "=&v"(hv[23]),
                  "=&v"(hv[24]), "=&v"(hv[25]), "=&v"(hv[26]), "=&v"(hv[27]),
                  "=&v"(hv[28]), "=&v"(hv[29]), "=&v"(hv[30]), "=&v"(hv[31])
                : "v"(hbase)
                : "memory");
            #pragma unroll
            for (int sg = 0; sg < 32; ++sg) {
                union { uint4 u; bf16x8 v; } hf; hf.u = hv[sg];
                const bf16x8 b0 = *(const bf16x8*)(wl + 16384 + sg * 1024);
                const bf16x8 b1 = *(const bf16x8*)(wl + 16384 + sg * 1024 + 128);
                acc[0][sg & 1] = __builtin_amdgcn_mfma_f32_16x16x32_bf16(hf.v, b0, acc[0][sg & 1], 0, 0, 0);
                acc[1][sg & 1] = __builtin_amdgcn_mfma_f32_16x16x32_bf16(hf.v, b1, acc[1][sg & 1], 0, 0, 0);
            }
        }
        const floatx4 av0 = acc[0][0] + acc[0][1];
        const floatx4 av1 = acc[1][0] + acc[1][1];

        // ---- in-register quad transpose ----
        float g0v[4] = {av0.x, av0.y, av0.z, av0.w};
        float g1v[4] = {av1.x, av1.y, av1.z, av1.w};
        quadT(g0v);
        quadT(g1v);

        // ---- prefetch x for t+1 (RTT hides under the cell update) ----
        if (t + 1 < T) loadx(t + 1);

        // ---- fused cell update: lane owns (row_l, j0) and (row_l, j0+1) ----
        const float i0 = 1.f / (1.f + expf(-(g0v[0] + bias0q.x)));
        const float f0 = 1.f / (1.f + expf(-(g0v[1] + bias0q.y)));
        const float o0 = 1.f / (1.f + expf(-(g0v[2] + bias0q.z)));
        const float t0 = tanhf(g0v[3] + bias0q.w);
        const float i1 = 1.f / (1.f + expf(-(g1v[0] + bias1q.x)));
        const float f1 = 1.f / (1.f + expf(-(g1v[1] + bias1q.y)));
        const float o1 = 1.f / (1.f + expf(-(g1v[2] + bias1q.z)));
        const float t1 = tanhf(g1v[3] + bias1q.w);
        c0 = f0 * c0 + i0 * t0;
        c1 = f1 * c1 + i1 * t1;
        const float hv0 = o0 * tanhf(c0);
        const float hv1 = o1 * tanhf(c1);
        const int j0 = gb * 8 + 2 * jl;      // even local j; pair (j0, j0+1)
        const int hi = row_l * H + j0;
        union { __bf16 h2[2]; unsigned u; } hp;
        hp.h2[0] = (__bf16)hv0; hp.h2[1] = (__bf16)hv1;
        __hip_atomic_store((unsigned*)&hnxt[hi], hp.u, __ATOMIC_RELAXED,
                           __HIP_MEMORY_SCOPE_AGENT);   // one 4B write-through
        if (t == T - 1) {
            const int gr = group * BG + row_l;
            hfin[gr * H + j0]     = hv0;
            hfin[gr * H + j0 + 1] = hv1;
        }

        __syncthreads();  // drain all threads' h stores (vmcnt0) before arrive

        // ---- arrive: leader STORES to its own line ----
        if (tid == 0)
            __hip_atomic_store(&bar->arr[gb][0], (unsigned)(t + 1),
                               __ATOMIC_RELAXED, __HIP_MEMORY_SCOPE_AGENT);

        // ---- x MFMAs for t+1 in the propagation shadow ----
        if (t + 1 < T) xmfma();
    }
}

// out[b,o] = h[b,:] . Why[o,:] + bhy[o]
__global__ __launch_bounds__(256) void out_gemm(
    const float* __restrict__ h, const float* __restrict__ Why,
    const float* __restrict__ bhy, float* __restrict__ out)
{
    const int idx = blockIdx.x * 256 + threadIdx.x;
    if (idx >= B * O) return;
    const int b = idx / O;
    const int o = idx % O;
    const float4* hv = (const float4*)&h[(size_t)b * H];
    const float4* wv = (const float4*)&Why[(size_t)o * H];
    float s = 0.f;
    #pragma unroll 4
    for (int k = 0; k < H / 4; ++k) {
        const float4 a = hv[k];
        const float4 w = wv[k];
        s += a.x * w.x + a.y * w.y + a.z * w.z + a.w * w.w;
    }
    out[idx] = s + bhy[o];
}

extern "C" void kernel_launch(void* const* d_in, const int* in_sizes, int n_in,
                              void* d_out, int out_size, void* d_ws, size_t ws_size,
                              hipStream_t stream) {
    const float* x   = (const float*)d_in[0];
    const float* Wx  = (const float*)d_in[1];
    const float* bx  = (const float*)d_in[2];
    const float* Wh  = (const float*)d_in[3];
    const float* bh  = (const float*)d_in[4];
    const float* Why = (const float*)d_in[5];
    const float* bhy = (const float*)d_in[6];
    float* out = (float*)d_out;

    // ws layout (~12.89 MB total, <= proven 12.90 MB):
    // Wc 12,582,912 | bias 16,384 @12,582,912 | hbufs 262,144 @12,599,296
    // bars 2 x 16,384 @12,861,440
    // hfin (256 KB fp32) aliases Wc[0:262144) — Wc only read during the
    // one-time LDS stage, 511 barriers before any t=T-1 write. Safe.
    char* ws = (char*)d_ws;
    __bf16* Wc    = (__bf16*)ws;
    float*  bias  = (float*)(ws + 12582912);
    __bf16* hbufs = (__bf16*)(ws + 12599296);   // [2][2][BG*H] = 256 KB
    GBar*   bars  = (GBar*)  (ws + 12861440);   // 2 x 16,384 B
    float*  hfin  = (float*)ws;

    (void)hipMemsetAsync(ws + 12599296, 0, 262144 + 2 * sizeof(GBar), stream);
    convert_w<<<3072, 256, 0, stream>>>(Wx, Wh, Wc);
    make_bias<<<16, 256, 0, stream>>>(bx, bh, bias);

    lstm_persistent<<<GROUPS * GBLK, 128, 0, stream>>>(x, Wc, bias, hbufs,
                                                       hfin, bars);

    out_gemm<<<(B * O + 255) / 256, 256, 0, stream>>>(hfin, Why, bhy, out);
}